// Round 1
// baseline (918.200 us; speedup 1.0000x reference)
//
#include <hip/hip_runtime.h>
#include <hip/hip_bf16.h>
#include <limits.h>

#define N_NODES 50000
#define N_EDGES 800000
#define HID 128
#define N_LAYER 3
#define FC_HID 256
#define N_CLASS 10
#define N_GRAPHS 64

// ---------------- edge-index min (ei = edge_index - min) ----------------
__global__ void k_min(const int* __restrict__ ei, int n, int* __restrict__ emin) {
    int v = INT_MAX;
    for (int i = blockIdx.x * blockDim.x + threadIdx.x; i < n; i += gridDim.x * blockDim.x)
        v = min(v, ei[i]);
#pragma unroll
    for (int off = 32; off > 0; off >>= 1)
        v = min(v, __shfl_down(v, off, 64));
    if ((threadIdx.x & 63) == 0) atomicMin(emin, v);
}

// ---------------- in-degree histogram ----------------
__global__ void k_deg(const int* __restrict__ ei, const int* __restrict__ emin,
                      int* __restrict__ deg) {
    int e = blockIdx.x * blockDim.x + threadIdx.x;
    if (e >= N_EDGES) return;
    int m = *emin;
    atomicAdd(&deg[ei[N_EDGES + e] - m], 1);
}

// ---------------- per-graph node counts ----------------
__global__ void k_counts(const int* __restrict__ batch, float* __restrict__ counts) {
    int n = blockIdx.x * blockDim.x + threadIdx.x;
    if (n < N_NODES) atomicAdd(&counts[batch[n]], 1.0f);
}

__global__ void k_invdeg(const int* __restrict__ deg, float* __restrict__ invd) {
    int n = blockIdx.x * blockDim.x + threadIdx.x;
    if (n < N_NODES) invd[n] = 1.0f / (float)max(deg[n], 1);
}

// ---------------- exclusive scan of deg -> row_ptr (single block) ----------------
__global__ void k_scan(const int* __restrict__ deg, int* __restrict__ rp) {
    __shared__ int sums[1024];
    const int t = threadIdx.x;
    const int chunk = (N_NODES + 1023) / 1024;  // 49
    int beg = t * chunk;
    int end = min(beg + chunk, N_NODES);
    int s = 0;
    for (int i = beg; i < end; ++i) s += deg[i];
    sums[t] = s;
    __syncthreads();
    for (int off = 1; off < 1024; off <<= 1) {
        int v = (t >= off) ? sums[t - off] : 0;
        __syncthreads();
        sums[t] += v;
        __syncthreads();
    }
    int run = (t == 0) ? 0 : sums[t - 1];
    for (int i = beg; i < end; ++i) { rp[i] = run; run += deg[i]; }
    if (t == 1023) rp[N_NODES] = run;  // empty chunk: run == total
}

// ---------------- scatter edges into CSR slots ----------------
__global__ void k_scatter(const int* __restrict__ ei, const int* __restrict__ emin,
                          const int* __restrict__ rp, int* __restrict__ fill,
                          int* __restrict__ csr) {
    int e = blockIdx.x * blockDim.x + threadIdx.x;
    if (e >= N_EDGES) return;
    int m = *emin;
    int s = ei[e] - m, d = ei[N_EDGES + e] - m;
    int pos = rp[d] + atomicAdd(&fill[d], 1);
    csr[pos] = s;
}

// ---------------- mean aggregation: one wave per node, float2/lane ----------------
__global__ void k_agg(const float* __restrict__ h, const int* __restrict__ rp,
                      const int* __restrict__ csr, const float* __restrict__ invd,
                      float* __restrict__ agg) {
    const int n = blockIdx.x;
    const int lane = threadIdx.x;  // 64
    int beg = rp[n], end = rp[n + 1];
    float a0 = 0, a1 = 0, b0 = 0, b1 = 0, c0 = 0, c1 = 0, d0 = 0, d1 = 0;
    int e = beg;
    for (; e + 4 <= end; e += 4) {  // 4-edge unroll for memory-level parallelism
        int s0 = csr[e], s1 = csr[e + 1], s2 = csr[e + 2], s3 = csr[e + 3];
        float2 v0 = *(const float2*)(h + (size_t)s0 * HID + lane * 2);
        float2 v1 = *(const float2*)(h + (size_t)s1 * HID + lane * 2);
        float2 v2 = *(const float2*)(h + (size_t)s2 * HID + lane * 2);
        float2 v3 = *(const float2*)(h + (size_t)s3 * HID + lane * 2);
        a0 += v0.x; a1 += v0.y; b0 += v1.x; b1 += v1.y;
        c0 += v2.x; c1 += v2.y; d0 += v3.x; d1 += v3.y;
    }
    for (; e < end; ++e) {
        int s = csr[e];
        float2 v = *(const float2*)(h + (size_t)s * HID + lane * 2);
        a0 += v.x; a1 += v.y;
    }
    float iv = invd[n];
    float2 r;
    r.x = (a0 + b0 + c0 + d0) * iv;
    r.y = (a1 + b1 + c1 + d1) * iv;
    *(float2*)(agg + (size_t)n * HID + lane * 2) = r;
}

// ---------------- fused: h_out = relu(agg@Wl + h@Wr + b); pooled += per-graph sums ----------------
// 64-row x 128-col tile, 256 threads: thread = (rg: 8 row-groups of 8 rows, cg: 32 col-groups of 4 cols)
__global__ __launch_bounds__(256, 2) void k_gemm(
    const float* __restrict__ agg, const float* __restrict__ hin,
    const float* __restrict__ Wl, const float* __restrict__ Wr,
    const float* __restrict__ bl, const int* __restrict__ batch,
    float* __restrict__ hout, float* __restrict__ pooled, int layer) {
    __shared__ float smem[12288];   // 48KB: As[64][32] Hs[64][32] Wls[32][128] Wrs[32][128]
    float* As = smem;
    float* Hs = smem + 2048;
    float* Wls = smem + 4096;
    float* Wrs = smem + 8192;

    const int tx = threadIdx.x;
    const int row0 = blockIdx.x * 64;
    const int cg = tx & 31, rg = tx >> 5;
    const int j0 = cg * 4;
    float acc[8][4];
#pragma unroll
    for (int m = 0; m < 8; ++m)
#pragma unroll
        for (int c = 0; c < 4; ++c) acc[m][c] = 0.f;

    for (int kk = 0; kk < HID; kk += 32) {
#pragma unroll
        for (int l = 0; l < 2; ++l) {  // stage A/H tiles: 64x32 each
            int lin = tx + l * 256;
            int r = lin >> 3, c4 = (lin & 7) * 4;
            int grow = row0 + r;
            float4 av = make_float4(0, 0, 0, 0), hv = make_float4(0, 0, 0, 0);
            if (grow < N_NODES) {
                av = *(const float4*)(agg + (size_t)grow * HID + kk + c4);
                hv = *(const float4*)(hin + (size_t)grow * HID + kk + c4);
            }
            *(float4*)&As[r * 32 + c4] = av;
            *(float4*)&Hs[r * 32 + c4] = hv;
        }
#pragma unroll
        for (int l = 0; l < 4; ++l) {  // stage W k-chunks: 32x128 each
            int lin = tx + l * 256;
            int kr = lin >> 5, jj = (lin & 31) * 4;
            *(float4*)&Wls[kr * 128 + jj] = *(const float4*)(Wl + (size_t)(kk + kr) * HID + jj);
            *(float4*)&Wrs[kr * 128 + jj] = *(const float4*)(Wr + (size_t)(kk + kr) * HID + jj);
        }
        __syncthreads();
#pragma unroll
        for (int k4 = 0; k4 < 32; k4 += 4) {
            float4 wl[4], wr[4];
#pragma unroll
            for (int u = 0; u < 4; ++u) {
                wl[u] = *(const float4*)&Wls[(k4 + u) * 128 + j0];
                wr[u] = *(const float4*)&Wrs[(k4 + u) * 128 + j0];
            }
#pragma unroll
            for (int m = 0; m < 8; ++m) {
                int r = rg * 8 + m;
                float4 a = *(const float4*)&As[r * 32 + k4];
                float4 hh = *(const float4*)&Hs[r * 32 + k4];
                const float* ap = (const float*)&a;
                const float* hp = (const float*)&hh;
#pragma unroll
                for (int u = 0; u < 4; ++u) {
                    const float* wlp = (const float*)&wl[u];
                    const float* wrp = (const float*)&wr[u];
#pragma unroll
                    for (int c = 0; c < 4; ++c) {
                        acc[m][c] = fmaf(ap[u], wlp[c], acc[m][c]);
                        acc[m][c] = fmaf(hp[u], wrp[c], acc[m][c]);
                    }
                }
            }
        }
        __syncthreads();
    }

    // epilogue: bias + relu, store h_out, block pre-reduce into pooled (batch is sorted)
    float b0 = bl[j0], b1 = bl[j0 + 1], b2 = bl[j0 + 2], b3 = bl[j0 + 3];
    float* Ts = smem;                 // reuse: [64][128]
    int* bs = (int*)(smem + 8192);    // [64]
    if (tx < 64) {
        int grow = row0 + tx;
        bs[tx] = (grow < N_NODES) ? batch[grow] : -1;
    }
#pragma unroll
    for (int m = 0; m < 8; ++m) {
        int r = rg * 8 + m;
        int grow = row0 + r;
        float4 v;
        v.x = fmaxf(acc[m][0] + b0, 0.f);
        v.y = fmaxf(acc[m][1] + b1, 0.f);
        v.z = fmaxf(acc[m][2] + b2, 0.f);
        v.w = fmaxf(acc[m][3] + b3, 0.f);
        *(float4*)&Ts[r * 128 + j0] = v;
        if (grow < N_NODES) *(float4*)(hout + (size_t)grow * HID + j0) = v;
    }
    __syncthreads();
    if (tx < 128) {
        int j = tx;
        float run = 0.f;
        int curb = bs[0];
#pragma unroll 4
        for (int r = 0; r < 64; ++r) {
            int bb = bs[r];
            if (bb != curb) {
                if (curb >= 0)
                    atomicAdd(&pooled[(size_t)curb * (HID * N_LAYER) + layer * HID + j], run);
                run = 0.f;
                curb = bb;
            }
            run += Ts[r * 128 + j];
        }
        if (curb >= 0)
            atomicAdd(&pooled[(size_t)curb * (HID * N_LAYER) + layer * HID + j], run);
    }
}

// ---------------- FC head: one block per graph ----------------
__global__ void k_fc(const float* __restrict__ pooled, const float* __restrict__ counts,
                     const float* __restrict__ fc1w, const float* __restrict__ fc1b,
                     const float* __restrict__ fc2w, const float* __restrict__ fc2b,
                     float* __restrict__ out) {
    __shared__ float pr[HID * N_LAYER];
    __shared__ float a1[FC_HID];
    const int g = blockIdx.x, t = threadIdx.x;  // 256 threads
    float invc = 1.0f / fmaxf(counts[g], 1.0f);
    for (int i = t; i < HID * N_LAYER; i += FC_HID)
        pr[i] = pooled[(size_t)g * (HID * N_LAYER) + i] * invc;
    __syncthreads();
    float acc = fc1b[t];
    for (int k = 0; k < HID * N_LAYER; ++k)
        acc = fmaf(pr[k], fc1w[(size_t)k * FC_HID + t], acc);
    a1[t] = fmaxf(acc, 0.f);
    __syncthreads();
    if (t < N_CLASS) {
        float o = fc2b[t];
        for (int k = 0; k < FC_HID; ++k)
            o = fmaf(a1[k], fc2w[(size_t)k * N_CLASS + t], o);
        out[(size_t)g * N_CLASS + t] = o;
    }
}

extern "C" void kernel_launch(void* const* d_in, const int* in_sizes, int n_in,
                              void* d_out, int out_size, void* d_ws, size_t ws_size,
                              hipStream_t stream) {
    const float* x = (const float*)d_in[0];
    const int* ei = (const int*)d_in[1];
    const int* batch = (const int*)d_in[2];
    const float* Wl = (const float*)d_in[3];
    const float* Wr = (const float*)d_in[4];
    const float* bl = (const float*)d_in[5];
    const float* fc1w = (const float*)d_in[6];
    const float* fc1b = (const float*)d_in[7];
    const float* fc2w = (const float*)d_in[8];
    const float* fc2b = (const float*)d_in[9];
    float* out = (float*)d_out;

    char* ws = (char*)d_ws;
    size_t off = 0;
    auto alloc = [&](size_t bytes) {
        void* p = ws + off;
        off += (bytes + 255) & ~size_t(255);
        return p;
    };
    int* emin = (int*)alloc(4);
    int* deg = (int*)alloc(N_NODES * 4);
    int* fill = (int*)alloc(N_NODES * 4);
    float* invd = (float*)alloc(N_NODES * 4);
    int* rp = (int*)alloc((N_NODES + 1) * 4);
    float* counts = (float*)alloc(N_GRAPHS * 4);
    float* pooled = (float*)alloc((size_t)N_GRAPHS * HID * N_LAYER * 4);
    int* csr = (int*)alloc((size_t)N_EDGES * 4);
    float* aggb = (float*)alloc((size_t)N_NODES * HID * 4);
    float* h1 = (float*)alloc((size_t)N_NODES * HID * 4);
    float* h2 = (float*)alloc((size_t)N_NODES * HID * 4);
    // total ws usage ~81 MB

    // zero accumulators every call (ws is poisoned once, never re-poisoned)
    hipMemsetAsync(emin, 0x7F, 4, stream);  // 0x7F7F7F7F > max index
    hipMemsetAsync(deg, 0, N_NODES * 4, stream);
    hipMemsetAsync(fill, 0, N_NODES * 4, stream);
    hipMemsetAsync(counts, 0, N_GRAPHS * 4, stream);
    hipMemsetAsync(pooled, 0, (size_t)N_GRAPHS * HID * N_LAYER * 4, stream);

    k_min<<<1024, 256, 0, stream>>>(ei, 2 * N_EDGES, emin);
    k_deg<<<(N_EDGES + 255) / 256, 256, 0, stream>>>(ei, emin, deg);
    k_counts<<<(N_NODES + 255) / 256, 256, 0, stream>>>(batch, counts);
    k_invdeg<<<(N_NODES + 255) / 256, 256, 0, stream>>>(deg, invd);
    k_scan<<<1, 1024, 0, stream>>>(deg, rp);
    k_scatter<<<(N_EDGES + 255) / 256, 256, 0, stream>>>(ei, emin, rp, fill, csr);

    const float* hin = x;
    float* houts[3] = {h1, h2, h1};
    for (int layer = 0; layer < N_LAYER; ++layer) {
        k_agg<<<N_NODES, 64, 0, stream>>>(hin, rp, csr, invd, aggb);
        k_gemm<<<(N_NODES + 63) / 64, 256, 0, stream>>>(
            aggb, hin, Wl + (size_t)layer * HID * HID, Wr + (size_t)layer * HID * HID,
            bl + (size_t)layer * HID, batch, houts[layer], pooled, layer);
        hin = houts[layer];
    }
    k_fc<<<N_GRAPHS, 256, 0, stream>>>(pooled, counts, fc1w, fc1b, fc2w, fc2b, out);
}

// Round 2
// 623.386 us; speedup vs baseline: 1.4729x; 1.4729x over previous
//
#include <hip/hip_runtime.h>
#include <hip/hip_bf16.h>
#include <limits.h>

#define N_NODES 50000
#define N_EDGES 800000
#define HID 128
#define N_LAYER 3
#define FC_HID 256
#define N_CLASS 10
#define N_GRAPHS 64

// ---------------- edge-index min (ei = edge_index - min) ----------------
__global__ void k_min(const int* __restrict__ ei, int n, int* __restrict__ emin) {
    int v = INT_MAX;
    for (int i = blockIdx.x * blockDim.x + threadIdx.x; i < n; i += gridDim.x * blockDim.x)
        v = min(v, ei[i]);
#pragma unroll
    for (int off = 32; off > 0; off >>= 1)
        v = min(v, __shfl_down(v, off, 64));
    if ((threadIdx.x & 63) == 0) atomicMin(emin, v);
}

// ---------------- in-degree histogram ----------------
__global__ void k_deg(const int* __restrict__ ei, const int* __restrict__ emin,
                      int* __restrict__ deg) {
    int e = blockIdx.x * blockDim.x + threadIdx.x;
    if (e >= N_EDGES) return;
    int m = *emin;
    atomicAdd(&deg[ei[N_EDGES + e] - m], 1);
}

// ---------------- per-graph node counts via binary search (batch is sorted) ----------------
__global__ void k_counts_bs(const int* __restrict__ batch, float* __restrict__ counts) {
    int g = threadIdx.x;  // 64 threads, 1 block
    if (g >= N_GRAPHS) return;
    // lower_bound(batch, g)
    int lo = 0, hi = N_NODES;
    while (lo < hi) { int mid = (lo + hi) >> 1; if (batch[mid] < g) lo = mid + 1; else hi = mid; }
    int lb = lo;
    // upper_bound(batch, g)
    lo = lb; hi = N_NODES;
    while (lo < hi) { int mid = (lo + hi) >> 1; if (batch[mid] <= g) lo = mid + 1; else hi = mid; }
    counts[g] = (float)(lo - lb);
}

__global__ void k_invdeg(const int* __restrict__ deg, float* __restrict__ invd) {
    int n = blockIdx.x * blockDim.x + threadIdx.x;
    if (n < N_NODES) invd[n] = 1.0f / (float)max(deg[n], 1);
}

// ---------------- exclusive scan of deg -> row_ptr (single block) ----------------
__global__ void k_scan(const int* __restrict__ deg, int* __restrict__ rp) {
    __shared__ int sums[1024];
    const int t = threadIdx.x;
    const int chunk = (N_NODES + 1023) / 1024;  // 49
    int beg = t * chunk;
    int end = min(beg + chunk, N_NODES);
    int s = 0;
    for (int i = beg; i < end; ++i) s += deg[i];
    sums[t] = s;
    __syncthreads();
    for (int off = 1; off < 1024; off <<= 1) {
        int v = (t >= off) ? sums[t - off] : 0;
        __syncthreads();
        sums[t] += v;
        __syncthreads();
    }
    int run = (t == 0) ? 0 : sums[t - 1];
    for (int i = beg; i < end; ++i) { rp[i] = run; run += deg[i]; }
    if (t == 1023) rp[N_NODES] = run;  // empty chunk: run == total
}

// ---------------- scatter edges into CSR slots ----------------
__global__ void k_scatter(const int* __restrict__ ei, const int* __restrict__ emin,
                          const int* __restrict__ rp, int* __restrict__ fill,
                          int* __restrict__ csr) {
    int e = blockIdx.x * blockDim.x + threadIdx.x;
    if (e >= N_EDGES) return;
    int m = *emin;
    int s = ei[e] - m, d = ei[N_EDGES + e] - m;
    int pos = rp[d] + atomicAdd(&fill[d], 1);
    csr[pos] = s;
}

// ---------------- mean aggregation: one wave per node, float2/lane ----------------
__global__ void k_agg(const float* __restrict__ h, const int* __restrict__ rp,
                      const int* __restrict__ csr, const float* __restrict__ invd,
                      float* __restrict__ agg) {
    const int n = blockIdx.x;
    const int lane = threadIdx.x;  // 64
    int beg = rp[n], end = rp[n + 1];
    float a0 = 0, a1 = 0, b0 = 0, b1 = 0, c0 = 0, c1 = 0, d0 = 0, d1 = 0;
    int e = beg;
    for (; e + 4 <= end; e += 4) {  // 4-edge unroll for memory-level parallelism
        int s0 = csr[e], s1 = csr[e + 1], s2 = csr[e + 2], s3 = csr[e + 3];
        float2 v0 = *(const float2*)(h + (size_t)s0 * HID + lane * 2);
        float2 v1 = *(const float2*)(h + (size_t)s1 * HID + lane * 2);
        float2 v2 = *(const float2*)(h + (size_t)s2 * HID + lane * 2);
        float2 v3 = *(const float2*)(h + (size_t)s3 * HID + lane * 2);
        a0 += v0.x; a1 += v0.y; b0 += v1.x; b1 += v1.y;
        c0 += v2.x; c1 += v2.y; d0 += v3.x; d1 += v3.y;
    }
    for (; e < end; ++e) {
        int s = csr[e];
        float2 v = *(const float2*)(h + (size_t)s * HID + lane * 2);
        a0 += v.x; a1 += v.y;
    }
    float iv = invd[n];
    float2 r;
    r.x = (a0 + b0 + c0 + d0) * iv;
    r.y = (a1 + b1 + c1 + d1) * iv;
    *(float2*)(agg + (size_t)n * HID + lane * 2) = r;
}

// ---------------- fused: h_out = relu(agg@Wl + h@Wr + b); pooled += per-graph sums ----------------
// 64-row x 128-col tile, 256 threads: thread = (rg: 8 row-groups of 8 rows, cg: 32 col-groups of 4 cols)
__global__ __launch_bounds__(256, 2) void k_gemm(
    const float* __restrict__ agg, const float* __restrict__ hin,
    const float* __restrict__ Wl, const float* __restrict__ Wr,
    const float* __restrict__ bl, const int* __restrict__ batch,
    float* __restrict__ hout, float* __restrict__ pooled, int layer) {
    __shared__ float smem[12288];   // 48KB: As[64][32] Hs[64][32] Wls[32][128] Wrs[32][128]
    float* As = smem;
    float* Hs = smem + 2048;
    float* Wls = smem + 4096;
    float* Wrs = smem + 8192;

    const int tx = threadIdx.x;
    const int row0 = blockIdx.x * 64;
    const int cg = tx & 31, rg = tx >> 5;
    const int j0 = cg * 4;
    float acc[8][4];
#pragma unroll
    for (int m = 0; m < 8; ++m)
#pragma unroll
        for (int c = 0; c < 4; ++c) acc[m][c] = 0.f;

    for (int kk = 0; kk < HID; kk += 32) {
#pragma unroll
        for (int l = 0; l < 2; ++l) {  // stage A/H tiles: 64x32 each
            int lin = tx + l * 256;
            int r = lin >> 3, c4 = (lin & 7) * 4;
            int grow = row0 + r;
            float4 av = make_float4(0, 0, 0, 0), hv = make_float4(0, 0, 0, 0);
            if (grow < N_NODES) {
                av = *(const float4*)(agg + (size_t)grow * HID + kk + c4);
                hv = *(const float4*)(hin + (size_t)grow * HID + kk + c4);
            }
            *(float4*)&As[r * 32 + c4] = av;
            *(float4*)&Hs[r * 32 + c4] = hv;
        }
#pragma unroll
        for (int l = 0; l < 4; ++l) {  // stage W k-chunks: 32x128 each
            int lin = tx + l * 256;
            int kr = lin >> 5, jj = (lin & 31) * 4;
            *(float4*)&Wls[kr * 128 + jj] = *(const float4*)(Wl + (size_t)(kk + kr) * HID + jj);
            *(float4*)&Wrs[kr * 128 + jj] = *(const float4*)(Wr + (size_t)(kk + kr) * HID + jj);
        }
        __syncthreads();
#pragma unroll
        for (int k4 = 0; k4 < 32; k4 += 4) {
            float4 wl[4], wr[4];
#pragma unroll
            for (int u = 0; u < 4; ++u) {
                wl[u] = *(const float4*)&Wls[(k4 + u) * 128 + j0];
                wr[u] = *(const float4*)&Wrs[(k4 + u) * 128 + j0];
            }
#pragma unroll
            for (int m = 0; m < 8; ++m) {
                int r = rg * 8 + m;
                float4 a = *(const float4*)&As[r * 32 + k4];
                float4 hh = *(const float4*)&Hs[r * 32 + k4];
                const float* ap = (const float*)&a;
                const float* hp = (const float*)&hh;
#pragma unroll
                for (int u = 0; u < 4; ++u) {
                    const float* wlp = (const float*)&wl[u];
                    const float* wrp = (const float*)&wr[u];
#pragma unroll
                    for (int c = 0; c < 4; ++c) {
                        acc[m][c] = fmaf(ap[u], wlp[c], acc[m][c]);
                        acc[m][c] = fmaf(hp[u], wrp[c], acc[m][c]);
                    }
                }
            }
        }
        __syncthreads();
    }

    // epilogue: bias + relu, store h_out, block pre-reduce into pooled (batch is sorted)
    float b0 = bl[j0], b1 = bl[j0 + 1], b2 = bl[j0 + 2], b3 = bl[j0 + 3];
    float* Ts = smem;                 // reuse: [64][128]
    int* bs = (int*)(smem + 8192);    // [64]
    if (tx < 64) {
        int grow = row0 + tx;
        bs[tx] = (grow < N_NODES) ? batch[grow] : -1;
    }
#pragma unroll
    for (int m = 0; m < 8; ++m) {
        int r = rg * 8 + m;
        int grow = row0 + r;
        float4 v;
        v.x = fmaxf(acc[m][0] + b0, 0.f);
        v.y = fmaxf(acc[m][1] + b1, 0.f);
        v.z = fmaxf(acc[m][2] + b2, 0.f);
        v.w = fmaxf(acc[m][3] + b3, 0.f);
        *(float4*)&Ts[r * 128 + j0] = v;
        if (grow < N_NODES) *(float4*)(hout + (size_t)grow * HID + j0) = v;
    }
    __syncthreads();
    if (tx < 128) {
        int j = tx;
        float run = 0.f;
        int curb = bs[0];
#pragma unroll 4
        for (int r = 0; r < 64; ++r) {
            int bb = bs[r];
            if (bb != curb) {
                if (curb >= 0)
                    atomicAdd(&pooled[(size_t)curb * (HID * N_LAYER) + layer * HID + j], run);
                run = 0.f;
                curb = bb;
            }
            run += Ts[r * 128 + j];
        }
        if (curb >= 0)
            atomicAdd(&pooled[(size_t)curb * (HID * N_LAYER) + layer * HID + j], run);
    }
}

// ---------------- FC head: one block per graph ----------------
__global__ void k_fc(const float* __restrict__ pooled, const float* __restrict__ counts,
                     const float* __restrict__ fc1w, const float* __restrict__ fc1b,
                     const float* __restrict__ fc2w, const float* __restrict__ fc2b,
                     float* __restrict__ out) {
    __shared__ float pr[HID * N_LAYER];
    __shared__ float a1[FC_HID];
    const int g = blockIdx.x, t = threadIdx.x;  // 256 threads
    float invc = 1.0f / fmaxf(counts[g], 1.0f);
    for (int i = t; i < HID * N_LAYER; i += FC_HID)
        pr[i] = pooled[(size_t)g * (HID * N_LAYER) + i] * invc;
    __syncthreads();
    float acc = fc1b[t];
    for (int k = 0; k < HID * N_LAYER; ++k)
        acc = fmaf(pr[k], fc1w[(size_t)k * FC_HID + t], acc);
    a1[t] = fmaxf(acc, 0.f);
    __syncthreads();
    if (t < N_CLASS) {
        float o = fc2b[t];
        for (int k = 0; k < FC_HID; ++k)
            o = fmaf(a1[k], fc2w[(size_t)k * N_CLASS + t], o);
        out[(size_t)g * N_CLASS + t] = o;
    }
}

extern "C" void kernel_launch(void* const* d_in, const int* in_sizes, int n_in,
                              void* d_out, int out_size, void* d_ws, size_t ws_size,
                              hipStream_t stream) {
    const float* x = (const float*)d_in[0];
    const int* ei = (const int*)d_in[1];
    const int* batch = (const int*)d_in[2];
    const float* Wl = (const float*)d_in[3];
    const float* Wr = (const float*)d_in[4];
    const float* bl = (const float*)d_in[5];
    const float* fc1w = (const float*)d_in[6];
    const float* fc1b = (const float*)d_in[7];
    const float* fc2w = (const float*)d_in[8];
    const float* fc2b = (const float*)d_in[9];
    float* out = (float*)d_out;

    char* ws = (char*)d_ws;
    size_t off = 0;
    auto alloc = [&](size_t bytes) {
        void* p = ws + off;
        off += (bytes + 255) & ~size_t(255);
        return p;
    };
    int* emin = (int*)alloc(4);
    int* deg = (int*)alloc(N_NODES * 4);
    int* fill = (int*)alloc(N_NODES * 4);
    float* invd = (float*)alloc(N_NODES * 4);
    int* rp = (int*)alloc((N_NODES + 1) * 4);
    float* counts = (float*)alloc(N_GRAPHS * 4);
    float* pooled = (float*)alloc((size_t)N_GRAPHS * HID * N_LAYER * 4);
    int* csr = (int*)alloc((size_t)N_EDGES * 4);
    float* aggb = (float*)alloc((size_t)N_NODES * HID * 4);
    float* h1 = (float*)alloc((size_t)N_NODES * HID * 4);
    float* h2 = (float*)alloc((size_t)N_NODES * HID * 4);
    // total ws usage ~81 MB

    // zero accumulators every call (ws is poisoned once, never re-poisoned)
    hipMemsetAsync(emin, 0x7F, 4, stream);  // 0x7F7F7F7F > max index
    hipMemsetAsync(deg, 0, N_NODES * 4, stream);
    hipMemsetAsync(fill, 0, N_NODES * 4, stream);
    hipMemsetAsync(pooled, 0, (size_t)N_GRAPHS * HID * N_LAYER * 4, stream);

    k_min<<<1024, 256, 0, stream>>>(ei, 2 * N_EDGES, emin);
    k_deg<<<(N_EDGES + 255) / 256, 256, 0, stream>>>(ei, emin, deg);
    k_counts_bs<<<1, 64, 0, stream>>>(batch, counts);
    k_invdeg<<<(N_NODES + 255) / 256, 256, 0, stream>>>(deg, invd);
    k_scan<<<1, 1024, 0, stream>>>(deg, rp);
    k_scatter<<<(N_EDGES + 255) / 256, 256, 0, stream>>>(ei, emin, rp, fill, csr);

    const float* hin = x;
    float* houts[3] = {h1, h2, h1};
    for (int layer = 0; layer < N_LAYER; ++layer) {
        k_agg<<<N_NODES, 64, 0, stream>>>(hin, rp, csr, invd, aggb);
        k_gemm<<<(N_NODES + 63) / 64, 256, 0, stream>>>(
            aggb, hin, Wl + (size_t)layer * HID * HID, Wr + (size_t)layer * HID * HID,
            bl + (size_t)layer * HID, batch, houts[layer], pooled, layer);
        hin = houts[layer];
    }
    k_fc<<<N_GRAPHS, 256, 0, stream>>>(pooled, counts, fc1w, fc1b, fc2w, fc2b, out);
}

// Round 3
// 468.413 us; speedup vs baseline: 1.9602x; 1.3308x over previous
//
#include <hip/hip_runtime.h>
#include <hip/hip_bf16.h>
#include <limits.h>

#define N_NODES 50000
#define N_EDGES 800000
#define HID 128
#define N_LAYER 3
#define FC_HID 256
#define N_CLASS 10
#define N_GRAPHS 64
#define SCAN_NB ((N_NODES + 255) / 256)  // 196

__device__ inline unsigned f2bf(float f) {  // RNE f32 -> bf16 bits
    unsigned u = __float_as_uint(f);
    return (u + 0x7FFFu + ((u >> 16) & 1u)) >> 16;
}

// ---------------- edge-index min ----------------
__global__ void k_min(const int* __restrict__ ei, int n, int* __restrict__ emin) {
    int v = INT_MAX;
    for (int i = blockIdx.x * blockDim.x + threadIdx.x; i < n; i += gridDim.x * blockDim.x)
        v = min(v, ei[i]);
#pragma unroll
    for (int off = 32; off > 0; off >>= 1)
        v = min(v, __shfl_down(v, off, 64));
    if ((threadIdx.x & 63) == 0) atomicMin(emin, v);
}

// ---------------- in-degree histogram ----------------
__global__ void k_deg(const int* __restrict__ ei, const int* __restrict__ emin,
                      int* __restrict__ deg) {
    int e = blockIdx.x * blockDim.x + threadIdx.x;
    if (e >= N_EDGES) return;
    int m = *emin;
    atomicAdd(&deg[ei[N_EDGES + e] - m], 1);
}

// ---------------- per-graph node counts via binary search (batch sorted) ----------------
__global__ void k_counts_bs(const int* __restrict__ batch, float* __restrict__ counts) {
    int g = threadIdx.x;
    if (g >= N_GRAPHS) return;
    int lo = 0, hi = N_NODES;
    while (lo < hi) { int mid = (lo + hi) >> 1; if (batch[mid] < g) lo = mid + 1; else hi = mid; }
    int lb = lo;
    lo = lb; hi = N_NODES;
    while (lo < hi) { int mid = (lo + hi) >> 1; if (batch[mid] <= g) lo = mid + 1; else hi = mid; }
    counts[g] = (float)(lo - lb);
}

__global__ void k_invdeg(const int* __restrict__ deg, float* __restrict__ invd) {
    int n = blockIdx.x * blockDim.x + threadIdx.x;
    if (n < N_NODES) invd[n] = 1.0f / (float)max(deg[n], 1);
}

// ---------------- hierarchical exclusive scan: deg -> rp ----------------
__global__ void k_scan1(const int* __restrict__ deg, int* __restrict__ bsum) {
    __shared__ int red[256];
    int t = threadIdx.x, i = blockIdx.x * 256 + t;
    red[t] = (i < N_NODES) ? deg[i] : 0;
    __syncthreads();
    for (int off = 128; off > 0; off >>= 1) {
        if (t < off) red[t] += red[t + off];
        __syncthreads();
    }
    if (t == 0) bsum[blockIdx.x] = red[0];
}

__global__ void k_scan2(const int* __restrict__ bsum, int* __restrict__ boff,
                        int* __restrict__ rp) {
    __shared__ int s[256];
    int t = threadIdx.x;
    int v = (t < SCAN_NB) ? bsum[t] : 0;
    s[t] = v;
    __syncthreads();
    for (int off = 1; off < 256; off <<= 1) {
        int u = (t >= off) ? s[t - off] : 0;
        __syncthreads();
        s[t] += u;
        __syncthreads();
    }
    if (t < SCAN_NB) boff[t] = s[t] - v;
    if (t == 255) rp[N_NODES] = s[255];
}

__global__ void k_scan3(const int* __restrict__ deg, const int* __restrict__ boff,
                        int* __restrict__ rp) {
    __shared__ int s[256];
    int t = threadIdx.x, i = blockIdx.x * 256 + t;
    int v = (i < N_NODES) ? deg[i] : 0;
    s[t] = v;
    __syncthreads();
    for (int off = 1; off < 256; off <<= 1) {
        int u = (t >= off) ? s[t - off] : 0;
        __syncthreads();
        s[t] += u;
        __syncthreads();
    }
    if (i < N_NODES) rp[i] = boff[blockIdx.x] + s[t] - v;
}

// ---------------- scatter edges into CSR slots ----------------
__global__ void k_scatter(const int* __restrict__ ei, const int* __restrict__ emin,
                          const int* __restrict__ rp, int* __restrict__ fill,
                          int* __restrict__ csr) {
    int e = blockIdx.x * blockDim.x + threadIdx.x;
    if (e >= N_EDGES) return;
    int m = *emin;
    int s = ei[e] - m, d = ei[N_EDGES + e] - m;
    int pos = rp[d] + atomicAdd(&fill[d], 1);
    csr[pos] = s;
}

// ---------------- fp32 -> bf16 conversion (x -> xb) ----------------
__global__ void k_cvt(const float* __restrict__ x, unsigned* __restrict__ xb, int n4) {
    int i = blockIdx.x * blockDim.x + threadIdx.x;  // 4 floats -> 2 packed uints
    if (i >= n4) return;
    float4 v = *(const float4*)(x + (size_t)i * 4);
    uint2 o;
    o.x = f2bf(v.x) | (f2bf(v.y) << 16);
    o.y = f2bf(v.z) | (f2bf(v.w) << 16);
    *(uint2*)(xb + (size_t)i * 2) = o;
}

// ---------------- mean aggregation: one wave per node, bf16 rows (256B/edge) ----------------
__global__ void k_agg(const unsigned* __restrict__ hb, const int* __restrict__ rp,
                      const int* __restrict__ csr, const float* __restrict__ invd,
                      float* __restrict__ agg) {
    const int n = blockIdx.x;
    const int lane = threadIdx.x;  // 64; lane covers features 2*lane, 2*lane+1
    int beg = rp[n], end = rp[n + 1];
    float p0 = 0, p1 = 0, q0 = 0, q1 = 0, r0 = 0, r1 = 0, t0 = 0, t1 = 0;
    int e = beg;
    for (; e + 8 <= end; e += 8) {  // 8-edge unroll for MLP
        int s0 = csr[e], s1 = csr[e + 1], s2 = csr[e + 2], s3 = csr[e + 3];
        int s4 = csr[e + 4], s5 = csr[e + 5], s6 = csr[e + 6], s7 = csr[e + 7];
        unsigned u0 = hb[(size_t)s0 * 64 + lane];
        unsigned u1 = hb[(size_t)s1 * 64 + lane];
        unsigned u2 = hb[(size_t)s2 * 64 + lane];
        unsigned u3 = hb[(size_t)s3 * 64 + lane];
        unsigned u4 = hb[(size_t)s4 * 64 + lane];
        unsigned u5 = hb[(size_t)s5 * 64 + lane];
        unsigned u6 = hb[(size_t)s6 * 64 + lane];
        unsigned u7 = hb[(size_t)s7 * 64 + lane];
        p0 += __uint_as_float(u0 << 16); p1 += __uint_as_float(u0 & 0xFFFF0000u);
        q0 += __uint_as_float(u1 << 16); q1 += __uint_as_float(u1 & 0xFFFF0000u);
        r0 += __uint_as_float(u2 << 16); r1 += __uint_as_float(u2 & 0xFFFF0000u);
        t0 += __uint_as_float(u3 << 16); t1 += __uint_as_float(u3 & 0xFFFF0000u);
        p0 += __uint_as_float(u4 << 16); p1 += __uint_as_float(u4 & 0xFFFF0000u);
        q0 += __uint_as_float(u5 << 16); q1 += __uint_as_float(u5 & 0xFFFF0000u);
        r0 += __uint_as_float(u6 << 16); r1 += __uint_as_float(u6 & 0xFFFF0000u);
        t0 += __uint_as_float(u7 << 16); t1 += __uint_as_float(u7 & 0xFFFF0000u);
    }
    for (; e < end; ++e) {
        unsigned u = hb[(size_t)csr[e] * 64 + lane];
        p0 += __uint_as_float(u << 16);
        p1 += __uint_as_float(u & 0xFFFF0000u);
    }
    float iv = invd[n];
    float2 r;
    r.x = (p0 + q0 + r0 + t0) * iv;
    r.y = (p1 + q1 + r1 + t1) * iv;
    *(float2*)(agg + (size_t)n * HID + lane * 2) = r;
}

// ---------------- fused: h_out = relu(agg@Wl + hin@Wr + b); pooled += per-graph sums ----------------
// 64-row x 128-col tile, BK=16 chunks, 33KB LDS -> 4 blocks/CU (50% occupancy)
__global__ __launch_bounds__(256, 4) void k_gemm(
    const float* __restrict__ agg, const unsigned* __restrict__ hinb,
    const float* __restrict__ Wl, const float* __restrict__ Wr,
    const float* __restrict__ bl, const int* __restrict__ batch,
    unsigned* __restrict__ houtb, float* __restrict__ pooled, int layer) {
    __shared__ float smem[8256];  // staging: As[64][16] Hs[64][16] Wls[16][128] Wrs[16][128] = 24KB
    float* As = smem;             // epilogue: Ts[64][128] (32KB) + bs[64]
    float* Hs = smem + 1024;
    float* Wls = smem + 2048;
    float* Wrs = smem + 4096;

    const int tx = threadIdx.x;
    const int row0 = blockIdx.x * 64;
    const int cg = tx & 31, rg = tx >> 5;
    const int j0 = cg * 4;
    const int ar = tx >> 2, ac = (tx & 3) * 4;   // A/H staging: 4 threads per row
    const int wkr = tx >> 5, wj = (tx & 31) * 4; // W staging
    float acc[8][4];
#pragma unroll
    for (int m = 0; m < 8; ++m)
#pragma unroll
        for (int c = 0; c < 4; ++c) acc[m][c] = 0.f;

    for (int kk = 0; kk < HID; kk += 16) {
        {   // stage A (fp32) and H (bf16 -> fp32) 64x16 tiles
            int grow = row0 + ar;
            float4 av = make_float4(0, 0, 0, 0), hv = make_float4(0, 0, 0, 0);
            if (grow < N_NODES) {
                av = *(const float4*)(agg + (size_t)grow * HID + kk + ac);
                uint2 hu = *(const uint2*)(hinb + (size_t)grow * 64 + ((kk + ac) >> 1));
                hv.x = __uint_as_float(hu.x << 16);
                hv.y = __uint_as_float(hu.x & 0xFFFF0000u);
                hv.z = __uint_as_float(hu.y << 16);
                hv.w = __uint_as_float(hu.y & 0xFFFF0000u);
            }
            *(float4*)&As[ar * 16 + ac] = av;
            *(float4*)&Hs[ar * 16 + ac] = hv;
        }
#pragma unroll
        for (int l = 0; l < 2; ++l) {  // stage W k-chunks 16x128
            int kr = wkr + l * 8;
            *(float4*)&Wls[kr * 128 + wj] = *(const float4*)(Wl + (size_t)(kk + kr) * HID + wj);
            *(float4*)&Wrs[kr * 128 + wj] = *(const float4*)(Wr + (size_t)(kk + kr) * HID + wj);
        }
        __syncthreads();
#pragma unroll
        for (int k4 = 0; k4 < 16; k4 += 4) {
            float4 wl[4], wr[4];
#pragma unroll
            for (int u = 0; u < 4; ++u) {
                wl[u] = *(const float4*)&Wls[(k4 + u) * 128 + j0];
                wr[u] = *(const float4*)&Wrs[(k4 + u) * 128 + j0];
            }
#pragma unroll
            for (int m = 0; m < 8; ++m) {
                int r = rg * 8 + m;
                float4 a = *(const float4*)&As[r * 16 + k4];
                float4 hh = *(const float4*)&Hs[r * 16 + k4];
                const float* ap = (const float*)&a;
                const float* hp = (const float*)&hh;
#pragma unroll
                for (int u = 0; u < 4; ++u) {
                    const float* wlp = (const float*)&wl[u];
                    const float* wrp = (const float*)&wr[u];
#pragma unroll
                    for (int c = 0; c < 4; ++c) {
                        acc[m][c] = fmaf(ap[u], wlp[c], acc[m][c]);
                        acc[m][c] = fmaf(hp[u], wrp[c], acc[m][c]);
                    }
                }
            }
        }
        __syncthreads();
    }

    // epilogue: bias + relu, store bf16 h_out, block pre-reduce into pooled (batch sorted)
    float b0 = bl[j0], b1 = bl[j0 + 1], b2 = bl[j0 + 2], b3 = bl[j0 + 3];
    float* Ts = smem;               // [64][128]
    int* bs = (int*)(smem + 8192);  // [64]
    if (tx < 64) {
        int grow = row0 + tx;
        bs[tx] = (grow < N_NODES) ? batch[grow] : -1;
    }
#pragma unroll
    for (int m = 0; m < 8; ++m) {
        int r = rg * 8 + m;
        int grow = row0 + r;
        float4 v;
        v.x = fmaxf(acc[m][0] + b0, 0.f);
        v.y = fmaxf(acc[m][1] + b1, 0.f);
        v.z = fmaxf(acc[m][2] + b2, 0.f);
        v.w = fmaxf(acc[m][3] + b3, 0.f);
        *(float4*)&Ts[r * 128 + j0] = v;
        if (grow < N_NODES) {
            uint2 o;
            o.x = f2bf(v.x) | (f2bf(v.y) << 16);
            o.y = f2bf(v.z) | (f2bf(v.w) << 16);
            *(uint2*)(houtb + (size_t)grow * 64 + (j0 >> 1)) = o;
        }
    }
    __syncthreads();
    if (tx < 128) {
        int j = tx;
        float run = 0.f;
        int curb = bs[0];
#pragma unroll 4
        for (int r = 0; r < 64; ++r) {
            int bb = bs[r];
            if (bb != curb) {
                if (curb >= 0)
                    atomicAdd(&pooled[(size_t)curb * (HID * N_LAYER) + layer * HID + j], run);
                run = 0.f;
                curb = bb;
            }
            run += Ts[r * 128 + j];
        }
        if (curb >= 0)
            atomicAdd(&pooled[(size_t)curb * (HID * N_LAYER) + layer * HID + j], run);
    }
}

// ---------------- FC head: one block per graph ----------------
__global__ void k_fc(const float* __restrict__ pooled, const float* __restrict__ counts,
                     const float* __restrict__ fc1w, const float* __restrict__ fc1b,
                     const float* __restrict__ fc2w, const float* __restrict__ fc2b,
                     float* __restrict__ out) {
    __shared__ float pr[HID * N_LAYER];
    __shared__ float a1[FC_HID];
    const int g = blockIdx.x, t = threadIdx.x;  // 256 threads
    float invc = 1.0f / fmaxf(counts[g], 1.0f);
    for (int i = t; i < HID * N_LAYER; i += FC_HID)
        pr[i] = pooled[(size_t)g * (HID * N_LAYER) + i] * invc;
    __syncthreads();
    float acc = fc1b[t];
    for (int k = 0; k < HID * N_LAYER; ++k)
        acc = fmaf(pr[k], fc1w[(size_t)k * FC_HID + t], acc);
    a1[t] = fmaxf(acc, 0.f);
    __syncthreads();
    if (t < N_CLASS) {
        float o = fc2b[t];
        for (int k = 0; k < FC_HID; ++k)
            o = fmaf(a1[k], fc2w[(size_t)k * N_CLASS + t], o);
        out[(size_t)g * N_CLASS + t] = o;
    }
}

extern "C" void kernel_launch(void* const* d_in, const int* in_sizes, int n_in,
                              void* d_out, int out_size, void* d_ws, size_t ws_size,
                              hipStream_t stream) {
    const float* x = (const float*)d_in[0];
    const int* ei = (const int*)d_in[1];
    const int* batch = (const int*)d_in[2];
    const float* Wl = (const float*)d_in[3];
    const float* Wr = (const float*)d_in[4];
    const float* bl = (const float*)d_in[5];
    const float* fc1w = (const float*)d_in[6];
    const float* fc1b = (const float*)d_in[7];
    const float* fc2w = (const float*)d_in[8];
    const float* fc2b = (const float*)d_in[9];
    float* out = (float*)d_out;

    char* ws = (char*)d_ws;
    size_t off = 0;
    auto alloc = [&](size_t bytes) {
        void* p = ws + off;
        off += (bytes + 255) & ~size_t(255);
        return p;
    };
    int* emin = (int*)alloc(4);
    int* deg = (int*)alloc(N_NODES * 4);
    int* fill = (int*)alloc(N_NODES * 4);
    float* invd = (float*)alloc(N_NODES * 4);
    int* rp = (int*)alloc((N_NODES + 1) * 4);
    float* counts = (float*)alloc(N_GRAPHS * 4);
    float* pooled = (float*)alloc((size_t)N_GRAPHS * HID * N_LAYER * 4);
    int* bsum = (int*)alloc(SCAN_NB * 4);
    int* boff = (int*)alloc(SCAN_NB * 4);
    int* csr = (int*)alloc((size_t)N_EDGES * 4);
    float* aggb = (float*)alloc((size_t)N_NODES * HID * 4);
    unsigned* xb = (unsigned*)alloc((size_t)N_NODES * 64 * 4);   // bf16x2 packed
    unsigned* hb1 = (unsigned*)alloc((size_t)N_NODES * 64 * 4);
    unsigned* hb2 = (unsigned*)alloc((size_t)N_NODES * 64 * 4);
    // total ws usage ~68 MB

    // zero accumulators every call (ws is poisoned once, never re-poisoned)
    hipMemsetAsync(emin, 0x7F, 4, stream);  // 0x7F7F7F7F > max index
    hipMemsetAsync(deg, 0, N_NODES * 4, stream);
    hipMemsetAsync(fill, 0, N_NODES * 4, stream);
    hipMemsetAsync(pooled, 0, (size_t)N_GRAPHS * HID * N_LAYER * 4, stream);

    k_min<<<1024, 256, 0, stream>>>(ei, 2 * N_EDGES, emin);
    k_deg<<<(N_EDGES + 255) / 256, 256, 0, stream>>>(ei, emin, deg);
    k_counts_bs<<<1, 64, 0, stream>>>(batch, counts);
    k_invdeg<<<(N_NODES + 255) / 256, 256, 0, stream>>>(deg, invd);
    k_scan1<<<SCAN_NB, 256, 0, stream>>>(deg, bsum);
    k_scan2<<<1, 256, 0, stream>>>(bsum, boff, rp);
    k_scan3<<<SCAN_NB, 256, 0, stream>>>(deg, boff, rp);
    k_scatter<<<(N_EDGES + 255) / 256, 256, 0, stream>>>(ei, emin, rp, fill, csr);
    k_cvt<<<(N_NODES * HID / 4 + 255) / 256, 256, 0, stream>>>(x, xb, N_NODES * HID / 4);

    const unsigned* hin = xb;
    unsigned* houts[3] = {hb1, hb2, hb1};
    for (int layer = 0; layer < N_LAYER; ++layer) {
        k_agg<<<N_NODES, 64, 0, stream>>>(hin, rp, csr, invd, aggb);
        k_gemm<<<(N_NODES + 63) / 64, 256, 0, stream>>>(
            aggb, hin, Wl + (size_t)layer * HID * HID, Wr + (size_t)layer * HID * HID,
            bl + (size_t)layer * HID, batch, houts[layer], pooled, layer);
        hin = houts[layer];
    }
    k_fc<<<N_GRAPHS, 256, 0, stream>>>(pooled, counts, fc1w, fc1b, fc2w, fc2b, out);
}

// Round 4
// 386.776 us; speedup vs baseline: 2.3740x; 1.2111x over previous
//
#include <hip/hip_runtime.h>
#include <hip/hip_bf16.h>
#include <limits.h>

#define N_NODES 50000
#define N_EDGES 800000
#define HID 128
#define N_LAYER 3
#define FC_HID 256
#define N_CLASS 10
#define N_GRAPHS 64
#define SCAN_NB ((N_NODES + 255) / 256)  // 196

typedef __attribute__((ext_vector_type(8))) short short8;   // 8 bf16 = 4 VGPRs
typedef __attribute__((ext_vector_type(4))) float f32x4;

__device__ inline unsigned f2bf(float f) {  // RNE f32 -> bf16 bits
    unsigned u = __float_as_uint(f);
    return (u + 0x7FFFu + ((u >> 16) & 1u)) >> 16;
}
__device__ inline float bf2f(unsigned b) { return __uint_as_float(b << 16); }

// ---------------- edge-index min ----------------
__global__ void k_min(const int* __restrict__ ei, int n, int* __restrict__ emin) {
    int v = INT_MAX;
    for (int i = blockIdx.x * blockDim.x + threadIdx.x; i < n; i += gridDim.x * blockDim.x)
        v = min(v, ei[i]);
#pragma unroll
    for (int off = 32; off > 0; off >>= 1)
        v = min(v, __shfl_down(v, off, 64));
    if ((threadIdx.x & 63) == 0) atomicMin(emin, v);
}

// ---------------- in-degree histogram ----------------
__global__ void k_deg(const int* __restrict__ ei, const int* __restrict__ emin,
                      int* __restrict__ deg) {
    int e = blockIdx.x * blockDim.x + threadIdx.x;
    if (e >= N_EDGES) return;
    int m = *emin;
    atomicAdd(&deg[ei[N_EDGES + e] - m], 1);
}

// ---------------- per-graph node counts via binary search (batch sorted) ----------------
__global__ void k_counts_bs(const int* __restrict__ batch, float* __restrict__ counts) {
    int g = threadIdx.x;
    if (g >= N_GRAPHS) return;
    int lo = 0, hi = N_NODES;
    while (lo < hi) { int mid = (lo + hi) >> 1; if (batch[mid] < g) lo = mid + 1; else hi = mid; }
    int lb = lo;
    lo = lb; hi = N_NODES;
    while (lo < hi) { int mid = (lo + hi) >> 1; if (batch[mid] <= g) lo = mid + 1; else hi = mid; }
    counts[g] = (float)(lo - lb);
}

__global__ void k_invdeg(const int* __restrict__ deg, float* __restrict__ invd) {
    int n = blockIdx.x * blockDim.x + threadIdx.x;
    if (n < N_NODES) invd[n] = 1.0f / (float)max(deg[n], 1);
}

// ---------------- hierarchical exclusive scan: deg -> rp ----------------
__global__ void k_scan1(const int* __restrict__ deg, int* __restrict__ bsum) {
    __shared__ int red[256];
    int t = threadIdx.x, i = blockIdx.x * 256 + t;
    red[t] = (i < N_NODES) ? deg[i] : 0;
    __syncthreads();
    for (int off = 128; off > 0; off >>= 1) {
        if (t < off) red[t] += red[t + off];
        __syncthreads();
    }
    if (t == 0) bsum[blockIdx.x] = red[0];
}

__global__ void k_scan2(const int* __restrict__ bsum, int* __restrict__ boff,
                        int* __restrict__ rp) {
    __shared__ int s[256];
    int t = threadIdx.x;
    int v = (t < SCAN_NB) ? bsum[t] : 0;
    s[t] = v;
    __syncthreads();
    for (int off = 1; off < 256; off <<= 1) {
        int u = (t >= off) ? s[t - off] : 0;
        __syncthreads();
        s[t] += u;
        __syncthreads();
    }
    if (t < SCAN_NB) boff[t] = s[t] - v;
    if (t == 255) rp[N_NODES] = s[255];
}

__global__ void k_scan3(const int* __restrict__ deg, const int* __restrict__ boff,
                        int* __restrict__ rp) {
    __shared__ int s[256];
    int t = threadIdx.x, i = blockIdx.x * 256 + t;
    int v = (i < N_NODES) ? deg[i] : 0;
    s[t] = v;
    __syncthreads();
    for (int off = 1; off < 256; off <<= 1) {
        int u = (t >= off) ? s[t - off] : 0;
        __syncthreads();
        s[t] += u;
        __syncthreads();
    }
    if (i < N_NODES) rp[i] = boff[blockIdx.x] + s[t] - v;
}

// ---------------- scatter edges into CSR slots ----------------
__global__ void k_scatter(const int* __restrict__ ei, const int* __restrict__ emin,
                          const int* __restrict__ rp, int* __restrict__ fill,
                          int* __restrict__ csr) {
    int e = blockIdx.x * blockDim.x + threadIdx.x;
    if (e >= N_EDGES) return;
    int m = *emin;
    int s = ei[e] - m, d = ei[N_EDGES + e] - m;
    int pos = rp[d] + atomicAdd(&fill[d], 1);
    csr[pos] = s;
}

// ---------------- fp32 -> bf16 conversion (x -> xb) ----------------
__global__ void k_cvt(const float* __restrict__ x, unsigned* __restrict__ xb, int n4) {
    int i = blockIdx.x * blockDim.x + threadIdx.x;
    if (i >= n4) return;
    float4 v = *(const float4*)(x + (size_t)i * 4);
    uint2 o;
    o.x = f2bf(v.x) | (f2bf(v.y) << 16);
    o.y = f2bf(v.z) | (f2bf(v.w) << 16);
    *(uint2*)(xb + (size_t)i * 2) = o;
}

// ---------------- W -> bf16 split-precision transposed: Wt[n][k], W ~= hi + lo ----------------
__global__ void k_prep(const float* __restrict__ Wl, const float* __restrict__ Wr,
                       unsigned* __restrict__ wlh, unsigned* __restrict__ wll,
                       unsigned* __restrict__ wrh, unsigned* __restrict__ wrl) {
    int b = blockIdx.x;  // 0..2: Wl layer b; 3..5: Wr layer b-3
    int t = threadIdx.x;
    const float* src = (b < 3) ? (Wl + (size_t)b * HID * HID) : (Wr + (size_t)(b - 3) * HID * HID);
    unsigned* dh = (b < 3) ? (wlh + (size_t)b * HID * 64) : (wrh + (size_t)(b - 3) * HID * 64);
    unsigned* dl = (b < 3) ? (wll + (size_t)b * HID * 64) : (wrl + (size_t)(b - 3) * HID * 64);
    for (int i = 0; i < 32; ++i) {
        int u = t * 32 + i;           // 0..8191: n = u>>6 (out col), kk = u&63 (k pair)
        int n = u >> 6, kk = u & 63;
        float v0 = src[(size_t)(2 * kk) * HID + n];
        float v1 = src[(size_t)(2 * kk + 1) * HID + n];
        unsigned h0 = f2bf(v0), h1 = f2bf(v1);
        unsigned l0 = f2bf(v0 - bf2f(h0)), l1 = f2bf(v1 - bf2f(h1));
        dh[u] = h0 | (h1 << 16);
        dl[u] = l0 | (l1 << 16);
    }
}

// ---------------- mean aggregation: one wave per node, bf16 rows, bf16 packed output ----------------
__global__ void k_agg(const unsigned* __restrict__ hb, const int* __restrict__ rp,
                      const int* __restrict__ csr, const float* __restrict__ invd,
                      unsigned* __restrict__ aggb) {
    const int n = blockIdx.x;
    const int lane = threadIdx.x;  // 64; lane covers features 2*lane, 2*lane+1
    int beg = rp[n], end = rp[n + 1];
    float p0 = 0, p1 = 0, q0 = 0, q1 = 0, r0 = 0, r1 = 0, t0 = 0, t1 = 0;
    int e = beg;
    for (; e + 8 <= end; e += 8) {
        int s0 = csr[e], s1 = csr[e + 1], s2 = csr[e + 2], s3 = csr[e + 3];
        int s4 = csr[e + 4], s5 = csr[e + 5], s6 = csr[e + 6], s7 = csr[e + 7];
        unsigned u0 = hb[(size_t)s0 * 64 + lane];
        unsigned u1 = hb[(size_t)s1 * 64 + lane];
        unsigned u2 = hb[(size_t)s2 * 64 + lane];
        unsigned u3 = hb[(size_t)s3 * 64 + lane];
        unsigned u4 = hb[(size_t)s4 * 64 + lane];
        unsigned u5 = hb[(size_t)s5 * 64 + lane];
        unsigned u6 = hb[(size_t)s6 * 64 + lane];
        unsigned u7 = hb[(size_t)s7 * 64 + lane];
        p0 += __uint_as_float(u0 << 16); p1 += __uint_as_float(u0 & 0xFFFF0000u);
        q0 += __uint_as_float(u1 << 16); q1 += __uint_as_float(u1 & 0xFFFF0000u);
        r0 += __uint_as_float(u2 << 16); r1 += __uint_as_float(u2 & 0xFFFF0000u);
        t0 += __uint_as_float(u3 << 16); t1 += __uint_as_float(u3 & 0xFFFF0000u);
        p0 += __uint_as_float(u4 << 16); p1 += __uint_as_float(u4 & 0xFFFF0000u);
        q0 += __uint_as_float(u5 << 16); q1 += __uint_as_float(u5 & 0xFFFF0000u);
        r0 += __uint_as_float(u6 << 16); r1 += __uint_as_float(u6 & 0xFFFF0000u);
        t0 += __uint_as_float(u7 << 16); t1 += __uint_as_float(u7 & 0xFFFF0000u);
    }
    for (; e < end; ++e) {
        unsigned u = hb[(size_t)csr[e] * 64 + lane];
        p0 += __uint_as_float(u << 16);
        p1 += __uint_as_float(u & 0xFFFF0000u);
    }
    float iv = invd[n];
    unsigned o = f2bf((p0 + q0 + r0 + t0) * iv) | (f2bf((p1 + q1 + r1 + t1) * iv) << 16);
    aggb[(size_t)n * 64 + lane] = o;
}

// ---------------- MFMA fused: h_out = relu(agg@Wl + hin@Wr + b); pooled += per-graph sums ----
// 64 rows x 128 cols per block, 4 waves; wave owns 32 cols x 64 rows.
// No LDS in main loop; fragments straight from global (W is L2-resident).
__global__ __launch_bounds__(256, 4) void k_gemm(
    const unsigned* __restrict__ aggb, const unsigned* __restrict__ hinb,
    const unsigned* __restrict__ wlh, const unsigned* __restrict__ wll,
    const unsigned* __restrict__ wrh, const unsigned* __restrict__ wrl,
    const float* __restrict__ bias, const int* __restrict__ batch,
    unsigned* __restrict__ houtb, float* __restrict__ pooled, int layer) {
    __shared__ float Ts[64 * 132];  // stride 132: epilogue writes <=2-way bank aliased
    __shared__ int bs[64];
    const int tx = threadIdx.x;
    const int wave = tx >> 6, lane = tx & 63;
    const int row0 = blockIdx.x * 64;
    const int lrow = lane & 15, kgrp = lane >> 4;

    if (tx < 64) {
        int grow = row0 + tx;
        bs[tx] = (grow < N_NODES) ? batch[grow] : -1;
    }

    f32x4 acc[4][2];
#pragma unroll
    for (int m = 0; m < 4; ++m)
#pragma unroll
        for (int n = 0; n < 2; ++n) acc[m][n] = (f32x4){0.f, 0.f, 0.f, 0.f};
    const short8 zf = {0, 0, 0, 0, 0, 0, 0, 0};

    for (int kc = 0; kc < 4; ++kc) {
        const int koff = kc * 16 + kgrp * 4;  // uint offset: k = kc*32 + kgrp*8 + (0..7)
        short8 af[4], hf[4];
#pragma unroll
        for (int m = 0; m < 4; ++m) {
            int r = row0 + m * 16 + lrow;
            if (r < N_NODES) {
                af[m] = *(const short8*)(aggb + (size_t)r * 64 + koff);
                hf[m] = *(const short8*)(hinb + (size_t)r * 64 + koff);
            } else {
                af[m] = zf;
                hf[m] = zf;
            }
        }
#pragma unroll
        for (int n = 0; n < 2; ++n) {
            int wn = wave * 2 + n;  // col tile 0..7
            size_t wbase = (size_t)(wn * 16 + lrow) * 64 + koff;
            short8 fl_h = *(const short8*)(wlh + wbase);
            short8 fl_l = *(const short8*)(wll + wbase);
            short8 fr_h = *(const short8*)(wrh + wbase);
            short8 fr_l = *(const short8*)(wrl + wbase);
#pragma unroll
            for (int m = 0; m < 4; ++m) {
                acc[m][n] = __builtin_amdgcn_mfma_f32_16x16x32_bf16(af[m], fl_h, acc[m][n], 0, 0, 0);
                acc[m][n] = __builtin_amdgcn_mfma_f32_16x16x32_bf16(af[m], fl_l, acc[m][n], 0, 0, 0);
                acc[m][n] = __builtin_amdgcn_mfma_f32_16x16x32_bf16(hf[m], fr_h, acc[m][n], 0, 0, 0);
                acc[m][n] = __builtin_amdgcn_mfma_f32_16x16x32_bf16(hf[m], fr_l, acc[m][n], 0, 0, 0);
            }
        }
    }

    // C/D layout: col = lane&15, row = (lane>>4)*4 + reg  [guide §3, m89-verified]
#pragma unroll
    for (int n = 0; n < 2; ++n) {
        int c = wave * 32 + n * 16 + lrow;
        float bb = bias[c];
#pragma unroll
        for (int m = 0; m < 4; ++m)
#pragma unroll
            for (int reg = 0; reg < 4; ++reg) {
                int r = m * 16 + kgrp * 4 + reg;
                Ts[r * 132 + c] = fmaxf(acc[m][n][reg] + bb, 0.f);
            }
    }
    __syncthreads();

    // bf16 h_out store, coalesced: 1024 uint4 tiles over [64][128]
#pragma unroll
    for (int it = 0; it < 4; ++it) {
        int f = it * 256 + tx;
        int r = f >> 4, slot = f & 15;
        int grow = row0 + r;
        if (grow < N_NODES) {
            const float* ts = &Ts[r * 132 + slot * 8];
            uint4 o;
            o.x = f2bf(ts[0]) | (f2bf(ts[1]) << 16);
            o.y = f2bf(ts[2]) | (f2bf(ts[3]) << 16);
            o.z = f2bf(ts[4]) | (f2bf(ts[5]) << 16);
            o.w = f2bf(ts[6]) | (f2bf(ts[7]) << 16);
            *(uint4*)(houtb + (size_t)grow * 64 + slot * 4) = o;
        }
    }

    // per-graph pooled pre-reduction (batch sorted; fp32 pre-quantization values)
    if (tx < 128) {
        int j = tx;
        float run = 0.f;
        int curb = bs[0];
        for (int r = 0; r < 64; ++r) {
            int bb = bs[r];
            if (bb != curb) {
                if (curb >= 0)
                    atomicAdd(&pooled[(size_t)curb * (HID * N_LAYER) + layer * HID + j], run);
                run = 0.f;
                curb = bb;
            }
            run += Ts[r * 132 + j];
        }
        if (curb >= 0)
            atomicAdd(&pooled[(size_t)curb * (HID * N_LAYER) + layer * HID + j], run);
    }
}

// ---------------- FC head: one block per graph ----------------
__global__ void k_fc(const float* __restrict__ pooled, const float* __restrict__ counts,
                     const float* __restrict__ fc1w, const float* __restrict__ fc1b,
                     const float* __restrict__ fc2w, const float* __restrict__ fc2b,
                     float* __restrict__ out) {
    __shared__ float pr[HID * N_LAYER];
    __shared__ float a1[FC_HID];
    const int g = blockIdx.x, t = threadIdx.x;  // 256 threads
    float invc = 1.0f / fmaxf(counts[g], 1.0f);
    for (int i = t; i < HID * N_LAYER; i += FC_HID)
        pr[i] = pooled[(size_t)g * (HID * N_LAYER) + i] * invc;
    __syncthreads();
    float acc = fc1b[t];
    for (int k = 0; k < HID * N_LAYER; ++k)
        acc = fmaf(pr[k], fc1w[(size_t)k * FC_HID + t], acc);
    a1[t] = fmaxf(acc, 0.f);
    __syncthreads();
    if (t < N_CLASS) {
        float o = fc2b[t];
        for (int k = 0; k < FC_HID; ++k)
            o = fmaf(a1[k], fc2w[(size_t)k * N_CLASS + t], o);
        out[(size_t)g * N_CLASS + t] = o;
    }
}

extern "C" void kernel_launch(void* const* d_in, const int* in_sizes, int n_in,
                              void* d_out, int out_size, void* d_ws, size_t ws_size,
                              hipStream_t stream) {
    const float* x = (const float*)d_in[0];
    const int* ei = (const int*)d_in[1];
    const int* batch = (const int*)d_in[2];
    const float* Wl = (const float*)d_in[3];
    const float* Wr = (const float*)d_in[4];
    const float* bl = (const float*)d_in[5];
    const float* fc1w = (const float*)d_in[6];
    const float* fc1b = (const float*)d_in[7];
    const float* fc2w = (const float*)d_in[8];
    const float* fc2b = (const float*)d_in[9];
    float* out = (float*)d_out;

    char* ws = (char*)d_ws;
    size_t off = 0;
    auto alloc = [&](size_t bytes) {
        void* p = ws + off;
        off += (bytes + 255) & ~size_t(255);
        return p;
    };
    int* emin = (int*)alloc(4);
    int* deg = (int*)alloc(N_NODES * 4);
    int* fill = (int*)alloc(N_NODES * 4);
    float* invd = (float*)alloc(N_NODES * 4);
    int* rp = (int*)alloc((N_NODES + 1) * 4);
    float* counts = (float*)alloc(N_GRAPHS * 4);
    float* pooled = (float*)alloc((size_t)N_GRAPHS * HID * N_LAYER * 4);
    int* bsum = (int*)alloc(SCAN_NB * 4);
    int* boff = (int*)alloc(SCAN_NB * 4);
    int* csr = (int*)alloc((size_t)N_EDGES * 4);
    unsigned* wlh = (unsigned*)alloc((size_t)N_LAYER * HID * 64 * 4);
    unsigned* wll = (unsigned*)alloc((size_t)N_LAYER * HID * 64 * 4);
    unsigned* wrh = (unsigned*)alloc((size_t)N_LAYER * HID * 64 * 4);
    unsigned* wrl = (unsigned*)alloc((size_t)N_LAYER * HID * 64 * 4);
    unsigned* aggb = (unsigned*)alloc((size_t)N_NODES * 64 * 4);   // bf16x2 packed
    unsigned* xb = (unsigned*)alloc((size_t)N_NODES * 64 * 4);
    unsigned* hb1 = (unsigned*)alloc((size_t)N_NODES * 64 * 4);
    unsigned* hb2 = (unsigned*)alloc((size_t)N_NODES * 64 * 4);
    // total ws usage ~56 MB

    // zero accumulators every call (ws is poisoned once, never re-poisoned)
    hipMemsetAsync(emin, 0x7F, 4, stream);  // 0x7F7F7F7F > max index
    hipMemsetAsync(deg, 0, N_NODES * 4, stream);
    hipMemsetAsync(fill, 0, N_NODES * 4, stream);
    hipMemsetAsync(pooled, 0, (size_t)N_GRAPHS * HID * N_LAYER * 4, stream);

    k_min<<<1024, 256, 0, stream>>>(ei, 2 * N_EDGES, emin);
    k_deg<<<(N_EDGES + 255) / 256, 256, 0, stream>>>(ei, emin, deg);
    k_counts_bs<<<1, 64, 0, stream>>>(batch, counts);
    k_invdeg<<<(N_NODES + 255) / 256, 256, 0, stream>>>(deg, invd);
    k_scan1<<<SCAN_NB, 256, 0, stream>>>(deg, bsum);
    k_scan2<<<1, 256, 0, stream>>>(bsum, boff, rp);
    k_scan3<<<SCAN_NB, 256, 0, stream>>>(deg, boff, rp);
    k_scatter<<<(N_EDGES + 255) / 256, 256, 0, stream>>>(ei, emin, rp, fill, csr);
    k_cvt<<<(N_NODES * HID / 4 + 255) / 256, 256, 0, stream>>>(x, xb, N_NODES * HID / 4);
    k_prep<<<6, 256, 0, stream>>>(Wl, Wr, wlh, wll, wrh, wrl);

    const unsigned* hin = xb;
    unsigned* houts[3] = {hb1, hb2, hb1};
    for (int layer = 0; layer < N_LAYER; ++layer) {
        k_agg<<<N_NODES, 64, 0, stream>>>(hin, rp, csr, invd, aggb);
        k_gemm<<<(N_NODES + 63) / 64, 256, 0, stream>>>(
            aggb, hin,
            wlh + (size_t)layer * HID * 64, wll + (size_t)layer * HID * 64,
            wrh + (size_t)layer * HID * 64, wrl + (size_t)layer * HID * 64,
            bl + (size_t)layer * HID, batch, houts[layer], pooled, layer);
        hin = houts[layer];
    }
    k_fc<<<N_GRAPHS, 256, 0, stream>>>(pooled, counts, fc1w, fc1b, fc2w, fc2b, out);
}

// Round 5
// 328.538 us; speedup vs baseline: 2.7948x; 1.1773x over previous
//
#include <hip/hip_runtime.h>
#include <hip/hip_bf16.h>
#include <limits.h>

#define N_NODES 50000
#define N_EDGES 800000
#define HID 128
#define N_LAYER 3
#define FC_HID 256
#define N_CLASS 10
#define N_GRAPHS 64
#define SCAN_NB ((N_NODES + 255) / 256)  // 196
#define NBKT 98                          // raw dst>>9, dst < 50000 -> 98 buckets

typedef __attribute__((ext_vector_type(8))) short short8;   // 8 bf16 = 4 VGPRs
typedef __attribute__((ext_vector_type(4))) float f32x4;

__device__ inline unsigned f2bf(float f) {  // RNE f32 -> bf16 bits
    unsigned u = __float_as_uint(f);
    return (u + 0x7FFFu + ((u >> 16) & 1u)) >> 16;
}
__device__ inline float bf2f(unsigned b) { return __uint_as_float(b << 16); }

// ---------------- fused: edge-index min + raw-dst bucket histogram ----------------
__global__ void k_minh(const int* __restrict__ ei, int* __restrict__ emin,
                       int* __restrict__ bhist) {
    __shared__ int red[256];
    __shared__ int lh[NBKT];
    int t = threadIdx.x;
    if (t < NBKT) lh[t] = 0;
    __syncthreads();
    int v = INT_MAX;
    for (int i = blockIdx.x * 256 + t; i < 2 * N_EDGES; i += gridDim.x * 256) {
        int e = ei[i];
        v = min(v, e);
        if (i >= N_EDGES) atomicAdd(&lh[e >> 9], 1);  // dst row: bucket histogram
    }
    red[t] = v;
    __syncthreads();
    for (int off = 128; off > 0; off >>= 1) {
        if (t < off) red[t] = min(red[t], red[t + off]);
        __syncthreads();
    }
    if (t == 0) atomicMin(emin, red[0]);
    if (t < NBKT && lh[t] > 0) atomicAdd(&bhist[t], lh[t]);
}

// ---------------- bucket scan (bboff) + per-graph counts (batch sorted) ----------------
__global__ void k_bscan(const int* __restrict__ bhist, int* __restrict__ bboff,
                        const int* __restrict__ batch, float* __restrict__ counts) {
    __shared__ int s[128];
    int t = threadIdx.x;  // 128 threads
    int v = (t < NBKT) ? bhist[t] : 0;
    s[t] = v;
    __syncthreads();
    for (int off = 1; off < 128; off <<= 1) {
        int u = (t >= off) ? s[t - off] : 0;
        __syncthreads();
        s[t] += u;
        __syncthreads();
    }
    if (t < NBKT) bboff[t] = s[t] - v;
    if (t == 127) bboff[NBKT] = s[127];
    if (t < N_GRAPHS) {
        int g = t;
        int lo = 0, hi = N_NODES;
        while (lo < hi) { int mid = (lo + hi) >> 1; if (batch[mid] < g) lo = mid + 1; else hi = mid; }
        int lb = lo;
        lo = lb; hi = N_NODES;
        while (lo < hi) { int mid = (lo + hi) >> 1; if (batch[mid] <= g) lo = mid + 1; else hi = mid; }
        counts[g] = (float)(lo - lb);
    }
}

// ---------------- bin edges by bucket (per-block LDS counting sort) + degree ----------------
__global__ void k_bin(const int* __restrict__ ei, const int* __restrict__ emin,
                      const int* __restrict__ bboff, int* __restrict__ bfill,
                      int* __restrict__ deg, unsigned* __restrict__ ebuf) {
    __shared__ int lcnt[NBKT];
    __shared__ int lbase[NBKT];
    int t = threadIdx.x;
    if (t < NBKT) lcnt[t] = 0;
    __syncthreads();
    int m = *emin;
    const int per = (N_EDGES + 255) / 256;  // grid = 256 blocks
    int e0 = blockIdx.x * per, e1 = min(e0 + per, N_EDGES);
    for (int e = e0 + t; e < e1; e += 256) {
        int d = ei[N_EDGES + e];
        atomicAdd(&lcnt[d >> 9], 1);
        atomicAdd(&deg[d - m], 1);
    }
    __syncthreads();
    if (t < NBKT) {
        int c = lcnt[t];
        lbase[t] = c ? (bboff[t] + atomicAdd(&bfill[t], c)) : 0;
        lcnt[t] = 0;
    }
    __syncthreads();
    for (int e = e0 + t; e < e1; e += 256) {
        int s = ei[e] - m;
        int d = ei[N_EDGES + e];
        int bk = d >> 9;
        int idx = atomicAdd(&lcnt[bk], 1);
        ebuf[lbase[bk] + idx] = ((unsigned)s << 9) | (unsigned)(d & 511);
    }
}

// ---------------- hierarchical exclusive scan: deg -> rp (+ invd fused) ----------------
__global__ void k_scan1(const int* __restrict__ deg, int* __restrict__ bsum) {
    __shared__ int red[256];
    int t = threadIdx.x, i = blockIdx.x * 256 + t;
    red[t] = (i < N_NODES) ? deg[i] : 0;
    __syncthreads();
    for (int off = 128; off > 0; off >>= 1) {
        if (t < off) red[t] += red[t + off];
        __syncthreads();
    }
    if (t == 0) bsum[blockIdx.x] = red[0];
}

__global__ void k_scan2(const int* __restrict__ bsum, int* __restrict__ boff,
                        int* __restrict__ rp) {
    __shared__ int s[256];
    int t = threadIdx.x;
    int v = (t < SCAN_NB) ? bsum[t] : 0;
    s[t] = v;
    __syncthreads();
    for (int off = 1; off < 256; off <<= 1) {
        int u = (t >= off) ? s[t - off] : 0;
        __syncthreads();
        s[t] += u;
        __syncthreads();
    }
    if (t < SCAN_NB) boff[t] = s[t] - v;
    if (t == 255) rp[N_NODES] = s[255];
}

__global__ void k_scan3(const int* __restrict__ deg, const int* __restrict__ boff,
                        int* __restrict__ rp, float* __restrict__ invd) {
    __shared__ int s[256];
    int t = threadIdx.x, i = blockIdx.x * 256 + t;
    int v = (i < N_NODES) ? deg[i] : 0;
    s[t] = v;
    __syncthreads();
    for (int off = 1; off < 256; off <<= 1) {
        int u = (t >= off) ? s[t - off] : 0;
        __syncthreads();
        s[t] += u;
        __syncthreads();
    }
    if (i < N_NODES) {
        rp[i] = boff[blockIdx.x] + s[t] - v;
        invd[i] = 1.0f / (float)max(v, 1);
    }
}

// ---------------- scatter within bucket windows: one block per bucket ----------------
__global__ void k_scatter2(const unsigned* __restrict__ ebuf, const int* __restrict__ bboff,
                           const int* __restrict__ rp, const int* __restrict__ emin,
                           int* __restrict__ csr) {
    __shared__ int lfill[512];
    __shared__ int lrp[512];
    int b = blockIdx.x, t = threadIdx.x;
    int m = *emin;
    int dbase = b << 9;
    for (int i = t; i < 512; i += 256) {
        lfill[i] = 0;
        int nd = dbase + i - m;
        lrp[i] = (nd >= 0 && nd < N_NODES) ? rp[nd] : 0;
    }
    __syncthreads();
    int beg = bboff[b], end = bboff[b + 1];
    for (int e = beg + t; e < end; e += 256) {
        unsigned p = ebuf[e];
        int loc = p & 511;
        int pos = lrp[loc] + atomicAdd(&lfill[loc], 1);
        csr[pos] = (int)(p >> 9);
    }
}

// ---------------- fp32 -> bf16 conversion (x -> xb) ----------------
__global__ void k_cvt(const float* __restrict__ x, unsigned* __restrict__ xb, int n4) {
    int i = blockIdx.x * blockDim.x + threadIdx.x;
    if (i >= n4) return;
    float4 v = *(const float4*)(x + (size_t)i * 4);
    uint2 o;
    o.x = f2bf(v.x) | (f2bf(v.y) << 16);
    o.y = f2bf(v.z) | (f2bf(v.w) << 16);
    *(uint2*)(xb + (size_t)i * 2) = o;
}

// ---------------- W -> bf16 split-precision transposed: Wt[n][k], W ~= hi + lo ----------------
__global__ void k_prep(const float* __restrict__ Wl, const float* __restrict__ Wr,
                       unsigned* __restrict__ wlh, unsigned* __restrict__ wll,
                       unsigned* __restrict__ wrh, unsigned* __restrict__ wrl) {
    int b = blockIdx.x;  // 0..2: Wl layer b; 3..5: Wr layer b-3
    int t = threadIdx.x;
    const float* src = (b < 3) ? (Wl + (size_t)b * HID * HID) : (Wr + (size_t)(b - 3) * HID * HID);
    unsigned* dh = (b < 3) ? (wlh + (size_t)b * HID * 64) : (wrh + (size_t)(b - 3) * HID * 64);
    unsigned* dl = (b < 3) ? (wll + (size_t)b * HID * 64) : (wrl + (size_t)(b - 3) * HID * 64);
    for (int i = 0; i < 32; ++i) {
        int u = t * 32 + i;           // 0..8191: n = u>>6 (out col), kk = u&63 (k pair)
        int n = u >> 6, kk = u & 63;
        float v0 = src[(size_t)(2 * kk) * HID + n];
        float v1 = src[(size_t)(2 * kk + 1) * HID + n];
        unsigned h0 = f2bf(v0), h1 = f2bf(v1);
        unsigned l0 = f2bf(v0 - bf2f(h0)), l1 = f2bf(v1 - bf2f(h1));
        dh[u] = h0 | (h1 << 16);
        dl[u] = l0 | (l1 << 16);
    }
}

// ---------------- mean aggregation: one wave per node, bf16 rows, bf16 packed output ----------------
__global__ void k_agg(const unsigned* __restrict__ hb, const int* __restrict__ rp,
                      const int* __restrict__ csr, const float* __restrict__ invd,
                      unsigned* __restrict__ aggb) {
    const int n = blockIdx.x;
    const int lane = threadIdx.x;  // 64; lane covers features 2*lane, 2*lane+1
    int beg = rp[n], end = rp[n + 1];
    float p0 = 0, p1 = 0, q0 = 0, q1 = 0, r0 = 0, r1 = 0, t0 = 0, t1 = 0;
    int e = beg;
    for (; e + 8 <= end; e += 8) {
        int s0 = csr[e], s1 = csr[e + 1], s2 = csr[e + 2], s3 = csr[e + 3];
        int s4 = csr[e + 4], s5 = csr[e + 5], s6 = csr[e + 6], s7 = csr[e + 7];
        unsigned u0 = hb[(size_t)s0 * 64 + lane];
        unsigned u1 = hb[(size_t)s1 * 64 + lane];
        unsigned u2 = hb[(size_t)s2 * 64 + lane];
        unsigned u3 = hb[(size_t)s3 * 64 + lane];
        unsigned u4 = hb[(size_t)s4 * 64 + lane];
        unsigned u5 = hb[(size_t)s5 * 64 + lane];
        unsigned u6 = hb[(size_t)s6 * 64 + lane];
        unsigned u7 = hb[(size_t)s7 * 64 + lane];
        p0 += __uint_as_float(u0 << 16); p1 += __uint_as_float(u0 & 0xFFFF0000u);
        q0 += __uint_as_float(u1 << 16); q1 += __uint_as_float(u1 & 0xFFFF0000u);
        r0 += __uint_as_float(u2 << 16); r1 += __uint_as_float(u2 & 0xFFFF0000u);
        t0 += __uint_as_float(u3 << 16); t1 += __uint_as_float(u3 & 0xFFFF0000u);
        p0 += __uint_as_float(u4 << 16); p1 += __uint_as_float(u4 & 0xFFFF0000u);
        q0 += __uint_as_float(u5 << 16); q1 += __uint_as_float(u5 & 0xFFFF0000u);
        r0 += __uint_as_float(u6 << 16); r1 += __uint_as_float(u6 & 0xFFFF0000u);
        t0 += __uint_as_float(u7 << 16); t1 += __uint_as_float(u7 & 0xFFFF0000u);
    }
    for (; e < end; ++e) {
        unsigned u = hb[(size_t)csr[e] * 64 + lane];
        p0 += __uint_as_float(u << 16);
        p1 += __uint_as_float(u & 0xFFFF0000u);
    }
    float iv = invd[n];
    unsigned o = f2bf((p0 + q0 + r0 + t0) * iv) | (f2bf((p1 + q1 + r1 + t1) * iv) << 16);
    aggb[(size_t)n * 64 + lane] = o;
}

// ---------------- MFMA fused: h_out = relu(agg@Wl + hin@Wr + b); pooled += per-graph sums ----
__global__ __launch_bounds__(256, 4) void k_gemm(
    const unsigned* __restrict__ aggb, const unsigned* __restrict__ hinb,
    const unsigned* __restrict__ wlh, const unsigned* __restrict__ wll,
    const unsigned* __restrict__ wrh, const unsigned* __restrict__ wrl,
    const float* __restrict__ bias, const int* __restrict__ batch,
    unsigned* __restrict__ houtb, float* __restrict__ pooled, int layer) {
    __shared__ float Ts[64 * 132];  // stride 132: epilogue writes <=2-way bank aliased
    __shared__ int bs[64];
    const int tx = threadIdx.x;
    const int wave = tx >> 6, lane = tx & 63;
    const int row0 = blockIdx.x * 64;
    const int lrow = lane & 15, kgrp = lane >> 4;

    if (tx < 64) {
        int grow = row0 + tx;
        bs[tx] = (grow < N_NODES) ? batch[grow] : -1;
    }

    f32x4 acc[4][2];
#pragma unroll
    for (int m = 0; m < 4; ++m)
#pragma unroll
        for (int n = 0; n < 2; ++n) acc[m][n] = (f32x4){0.f, 0.f, 0.f, 0.f};
    const short8 zf = {0, 0, 0, 0, 0, 0, 0, 0};

    for (int kc = 0; kc < 4; ++kc) {
        const int koff = kc * 16 + kgrp * 4;  // uint offset: k = kc*32 + kgrp*8 + (0..7)
        short8 af[4], hf[4];
#pragma unroll
        for (int m = 0; m < 4; ++m) {
            int r = row0 + m * 16 + lrow;
            if (r < N_NODES) {
                af[m] = *(const short8*)(aggb + (size_t)r * 64 + koff);
                hf[m] = *(const short8*)(hinb + (size_t)r * 64 + koff);
            } else {
                af[m] = zf;
                hf[m] = zf;
            }
        }
#pragma unroll
        for (int n = 0; n < 2; ++n) {
            int wn = wave * 2 + n;  // col tile 0..7
            size_t wbase = (size_t)(wn * 16 + lrow) * 64 + koff;
            short8 fl_h = *(const short8*)(wlh + wbase);
            short8 fl_l = *(const short8*)(wll + wbase);
            short8 fr_h = *(const short8*)(wrh + wbase);
            short8 fr_l = *(const short8*)(wrl + wbase);
#pragma unroll
            for (int m = 0; m < 4; ++m) {
                acc[m][n] = __builtin_amdgcn_mfma_f32_16x16x32_bf16(af[m], fl_h, acc[m][n], 0, 0, 0);
                acc[m][n] = __builtin_amdgcn_mfma_f32_16x16x32_bf16(af[m], fl_l, acc[m][n], 0, 0, 0);
                acc[m][n] = __builtin_amdgcn_mfma_f32_16x16x32_bf16(hf[m], fr_h, acc[m][n], 0, 0, 0);
                acc[m][n] = __builtin_amdgcn_mfma_f32_16x16x32_bf16(hf[m], fr_l, acc[m][n], 0, 0, 0);
            }
        }
    }

    // C/D layout: col = lane&15, row = (lane>>4)*4 + reg  [guide §3, m89-verified]
#pragma unroll
    for (int n = 0; n < 2; ++n) {
        int c = wave * 32 + n * 16 + lrow;
        float bb = bias[c];
#pragma unroll
        for (int m = 0; m < 4; ++m)
#pragma unroll
            for (int reg = 0; reg < 4; ++reg) {
                int r = m * 16 + kgrp * 4 + reg;
                Ts[r * 132 + c] = fmaxf(acc[m][n][reg] + bb, 0.f);
            }
    }
    __syncthreads();

    // bf16 h_out store, coalesced: 1024 uint4 tiles over [64][128]
#pragma unroll
    for (int it = 0; it < 4; ++it) {
        int f = it * 256 + tx;
        int r = f >> 4, slot = f & 15;
        int grow = row0 + r;
        if (grow < N_NODES) {
            const float* ts = &Ts[r * 132 + slot * 8];
            uint4 o;
            o.x = f2bf(ts[0]) | (f2bf(ts[1]) << 16);
            o.y = f2bf(ts[2]) | (f2bf(ts[3]) << 16);
            o.z = f2bf(ts[4]) | (f2bf(ts[5]) << 16);
            o.w = f2bf(ts[6]) | (f2bf(ts[7]) << 16);
            *(uint4*)(houtb + (size_t)grow * 64 + slot * 4) = o;
        }
    }

    // per-graph pooled pre-reduction (batch sorted; fp32 pre-quantization values)
    if (tx < 128) {
        int j = tx;
        float run = 0.f;
        int curb = bs[0];
        for (int r = 0; r < 64; ++r) {
            int bb = bs[r];
            if (bb != curb) {
                if (curb >= 0)
                    atomicAdd(&pooled[(size_t)curb * (HID * N_LAYER) + layer * HID + j], run);
                run = 0.f;
                curb = bb;
            }
            run += Ts[r * 132 + j];
        }
        if (curb >= 0)
            atomicAdd(&pooled[(size_t)curb * (HID * N_LAYER) + layer * HID + j], run);
    }
}

// ---------------- FC head: one block per graph ----------------
__global__ void k_fc(const float* __restrict__ pooled, const float* __restrict__ counts,
                     const float* __restrict__ fc1w, const float* __restrict__ fc1b,
                     const float* __restrict__ fc2w, const float* __restrict__ fc2b,
                     float* __restrict__ out) {
    __shared__ float pr[HID * N_LAYER];
    __shared__ float a1[FC_HID];
    const int g = blockIdx.x, t = threadIdx.x;  // 256 threads
    float invc = 1.0f / fmaxf(counts[g], 1.0f);
    for (int i = t; i < HID * N_LAYER; i += FC_HID)
        pr[i] = pooled[(size_t)g * (HID * N_LAYER) + i] * invc;
    __syncthreads();
    float acc = fc1b[t];
    for (int k = 0; k < HID * N_LAYER; ++k)
        acc = fmaf(pr[k], fc1w[(size_t)k * FC_HID + t], acc);
    a1[t] = fmaxf(acc, 0.f);
    __syncthreads();
    if (t < N_CLASS) {
        float o = fc2b[t];
        for (int k = 0; k < FC_HID; ++k)
            o = fmaf(a1[k], fc2w[(size_t)k * N_CLASS + t], o);
        out[(size_t)g * N_CLASS + t] = o;
    }
}

extern "C" void kernel_launch(void* const* d_in, const int* in_sizes, int n_in,
                              void* d_out, int out_size, void* d_ws, size_t ws_size,
                              hipStream_t stream) {
    const float* x = (const float*)d_in[0];
    const int* ei = (const int*)d_in[1];
    const int* batch = (const int*)d_in[2];
    const float* Wl = (const float*)d_in[3];
    const float* Wr = (const float*)d_in[4];
    const float* bl = (const float*)d_in[5];
    const float* fc1w = (const float*)d_in[6];
    const float* fc1b = (const float*)d_in[7];
    const float* fc2w = (const float*)d_in[8];
    const float* fc2b = (const float*)d_in[9];
    float* out = (float*)d_out;

    char* ws = (char*)d_ws;
    size_t off = 0;
    auto alloc = [&](size_t bytes) {
        void* p = ws + off;
        off += (bytes + 255) & ~size_t(255);
        return p;
    };
    int* emin = (int*)alloc(4);
    // ---- contiguous zero-group: deg .. pooled ----
    int* deg = (int*)alloc(N_NODES * 4);
    int* bhist = (int*)alloc(NBKT * 4);
    int* bfill = (int*)alloc(NBKT * 4);
    float* pooled = (float*)alloc((size_t)N_GRAPHS * HID * N_LAYER * 4);
    size_t zero_span = (size_t)((char*)(pooled + (size_t)N_GRAPHS * HID * N_LAYER) - (char*)deg);
    // ---- not zeroed (fully overwritten every call) ----
    float* invd = (float*)alloc(N_NODES * 4);
    int* rp = (int*)alloc((N_NODES + 1) * 4);
    float* counts = (float*)alloc(N_GRAPHS * 4);
    int* bsum = (int*)alloc(SCAN_NB * 4);
    int* boff = (int*)alloc(SCAN_NB * 4);
    int* bboff = (int*)alloc((NBKT + 1) * 4);
    unsigned* ebuf = (unsigned*)alloc((size_t)N_EDGES * 4);
    int* csr = (int*)alloc((size_t)N_EDGES * 4);
    unsigned* wlh = (unsigned*)alloc((size_t)N_LAYER * HID * 64 * 4);
    unsigned* wll = (unsigned*)alloc((size_t)N_LAYER * HID * 64 * 4);
    unsigned* wrh = (unsigned*)alloc((size_t)N_LAYER * HID * 64 * 4);
    unsigned* wrl = (unsigned*)alloc((size_t)N_LAYER * HID * 64 * 4);
    unsigned* aggb = (unsigned*)alloc((size_t)N_NODES * 64 * 4);   // bf16x2 packed
    unsigned* xb = (unsigned*)alloc((size_t)N_NODES * 64 * 4);
    unsigned* hb1 = (unsigned*)alloc((size_t)N_NODES * 64 * 4);
    unsigned* hb2 = (unsigned*)alloc((size_t)N_NODES * 64 * 4);

    // zero accumulators every call (ws is poisoned once, never re-poisoned)
    hipMemsetAsync(emin, 0x7F, 4, stream);       // 0x7F7F7F7F > max index
    hipMemsetAsync(deg, 0, zero_span, stream);   // deg, bhist, bfill, pooled (+pad)

    k_minh<<<128, 256, 0, stream>>>(ei, emin, bhist);
    k_bscan<<<1, 128, 0, stream>>>(bhist, bboff, batch, counts);
    k_bin<<<256, 256, 0, stream>>>(ei, emin, bboff, bfill, deg, ebuf);
    k_scan1<<<SCAN_NB, 256, 0, stream>>>(deg, bsum);
    k_scan2<<<1, 256, 0, stream>>>(bsum, boff, rp);
    k_scan3<<<SCAN_NB, 256, 0, stream>>>(deg, boff, rp, invd);
    k_scatter2<<<NBKT, 256, 0, stream>>>(ebuf, bboff, rp, emin, csr);
    k_cvt<<<(N_NODES * HID / 4 + 255) / 256, 256, 0, stream>>>(x, xb, N_NODES * HID / 4);
    k_prep<<<6, 256, 0, stream>>>(Wl, Wr, wlh, wll, wrh, wrl);

    const unsigned* hin = xb;
    unsigned* houts[3] = {hb1, hb2, hb1};
    for (int layer = 0; layer < N_LAYER; ++layer) {
        k_agg<<<N_NODES, 64, 0, stream>>>(hin, rp, csr, invd, aggb);
        k_gemm<<<(N_NODES + 63) / 64, 256, 0, stream>>>(
            aggb, hin,
            wlh + (size_t)layer * HID * 64, wll + (size_t)layer * HID * 64,
            wrh + (size_t)layer * HID * 64, wrl + (size_t)layer * HID * 64,
            bl + (size_t)layer * HID, batch, houts[layer], pooled, layer);
        hin = houts[layer];
    }
    k_fc<<<N_GRAPHS, 256, 0, stream>>>(pooled, counts, fc1w, fc1b, fc2w, fc2b, out);
}

// Round 6
// 277.216 us; speedup vs baseline: 3.3122x; 1.1851x over previous
//
#include <hip/hip_runtime.h>
#include <hip/hip_bf16.h>
#include <limits.h>

#define N_NODES 50000
#define N_EDGES 800000
#define HID 128
#define N_LAYER 3
#define FC_HID 256
#define N_CLASS 10
#define N_GRAPHS 64
#define NBKT 98                          // raw dst>>9; raw dst < 50000 -> buckets 0..97
#define BIN_NB 256                       // edge-slice blocks (k_minh / k_bin must match)
#define PER_BLK ((N_EDGES + BIN_NB - 1) / BIN_NB)  // 3125

typedef __attribute__((ext_vector_type(8))) short short8;   // 8 bf16 = 4 VGPRs
typedef __attribute__((ext_vector_type(4))) float f32x4;

__device__ inline unsigned f2bf(float f) {  // RNE f32 -> bf16 bits
    unsigned u = __float_as_uint(f);
    return (u + 0x7FFFu + ((u >> 16) & 1u)) >> 16;
}
__device__ inline float bf2f(unsigned b) { return __uint_as_float(b << 16); }

// ---------------- fused: edge-index min + per-(block,bucket) dst histogram ----------------
__global__ __launch_bounds__(512) void k_minh(const int* __restrict__ ei,
                                              int* __restrict__ emin,
                                              int* __restrict__ hist) {
    __shared__ int red[512];
    __shared__ int lh[NBKT];
    int t = threadIdx.x;
    if (t < NBKT) lh[t] = 0;
    __syncthreads();
    int e0 = blockIdx.x * PER_BLK, e1 = min(e0 + PER_BLK, N_EDGES);
    int v = INT_MAX;
    for (int j = e0 + t; j < e1; j += 512) {
        int s = ei[j], d = ei[N_EDGES + j];
        v = min(v, min(s, d));
        atomicAdd(&lh[d >> 9], 1);
    }
    red[t] = v;
    __syncthreads();
    for (int off = 256; off > 0; off >>= 1) {
        if (t < off) red[t] = min(red[t], red[t + off]);
        __syncthreads();
    }
    if (t == 0) atomicMin(emin, red[0]);
    if (t < NBKT) hist[blockIdx.x * NBKT + t] = lh[t];
}

// ---------------- per-bucket column scan over blocks: colex + bucket totals ----------------
__global__ void k_base(const int* __restrict__ hist, int* __restrict__ colex,
                       int* __restrict__ btot) {
    __shared__ int s[BIN_NB];
    int b = blockIdx.x, t = threadIdx.x;  // 256 threads
    int v = hist[t * NBKT + b];
    s[t] = v;
    __syncthreads();
    for (int off = 1; off < BIN_NB; off <<= 1) {
        int u = (t >= off) ? s[t - off] : 0;
        __syncthreads();
        s[t] += u;
        __syncthreads();
    }
    colex[t * NBKT + b] = s[t] - v;
    if (t == BIN_NB - 1) btot[b] = s[t];
}

// ---------------- bucket scan (bboff, rp[N]) + per-graph counts (batch sorted) ----------------
__global__ void k_bscan(const int* __restrict__ btot, int* __restrict__ bboff,
                        int* __restrict__ rp, const int* __restrict__ batch,
                        float* __restrict__ counts) {
    __shared__ int s[128];
    int t = threadIdx.x;  // 128 threads
    int v = (t < NBKT) ? btot[t] : 0;
    s[t] = v;
    __syncthreads();
    for (int off = 1; off < 128; off <<= 1) {
        int u = (t >= off) ? s[t - off] : 0;
        __syncthreads();
        s[t] += u;
        __syncthreads();
    }
    if (t < NBKT) bboff[t] = s[t] - v;
    if (t == 127) { bboff[NBKT] = s[127]; rp[N_NODES] = s[127]; }
    if (t < N_GRAPHS) {
        int g = t;
        int lo = 0, hi = N_NODES;
        while (lo < hi) { int mid = (lo + hi) >> 1; if (batch[mid] < g) lo = mid + 1; else hi = mid; }
        int lb = lo;
        lo = lb; hi = N_NODES;
        while (lo < hi) { int mid = (lo + hi) >> 1; if (batch[mid] <= g) lo = mid + 1; else hi = mid; }
        counts[g] = (float)(lo - lb);
    }
}

// ---------------- single-pass binning: edge -> bucket-contiguous packed ebuf ----------------
__global__ __launch_bounds__(512) void k_bin(const int* __restrict__ ei,
                                             const int* __restrict__ emin,
                                             const int* __restrict__ bboff,
                                             const int* __restrict__ colex,
                                             unsigned* __restrict__ ebuf) {
    __shared__ int lcnt[NBKT];
    __shared__ int lbase[NBKT];
    int t = threadIdx.x, blk = blockIdx.x;
    if (t < NBKT) {
        lcnt[t] = 0;
        lbase[t] = bboff[t] + colex[blk * NBKT + t];
    }
    __syncthreads();
    int m = *emin;
    int e0 = blk * PER_BLK, e1 = min(e0 + PER_BLK, N_EDGES);
    for (int j = e0 + t; j < e1; j += 512) {
        int s = ei[j] - m, d = ei[N_EDGES + j];
        int bk = d >> 9;
        int idx = atomicAdd(&lcnt[bk], 1);
        ebuf[lbase[bk] + idx] = ((unsigned)s << 9) | (unsigned)(d & 511);
    }
}

// ---------------- per-bucket: local deg/scan -> rp, invd, then CSR placement ----------------
__global__ __launch_bounds__(512) void k_scatter2(const unsigned* __restrict__ ebuf,
                                                  const int* __restrict__ bboff,
                                                  const int* __restrict__ emin,
                                                  int* __restrict__ rp,
                                                  float* __restrict__ invd,
                                                  int* __restrict__ csr) {
    __shared__ int ldeg[512];
    __shared__ int lsc[512];
    __shared__ int lfill[512];
    int b = blockIdx.x, t = threadIdx.x;
    int m = *emin;
    if (b == NBKT) {  // tail guard: nodes past bucket coverage (non-empty only if m > 176)
        for (int nd = NBKT * 512 - m + t; nd < N_NODES; nd += 512)
            if (nd >= 0) { rp[nd] = N_EDGES; invd[nd] = 1.0f; }
        return;
    }
    ldeg[t] = 0;
    lfill[t] = 0;
    __syncthreads();
    int beg = bboff[b], end = bboff[b + 1];
    for (int e = beg + t; e < end; e += 512)
        atomicAdd(&ldeg[ebuf[e] & 511], 1);
    __syncthreads();
    int v = ldeg[t];
    lsc[t] = v;
    __syncthreads();
    for (int off = 1; off < 512; off <<= 1) {
        int u = (t >= off) ? lsc[t - off] : 0;
        __syncthreads();
        lsc[t] += u;
        __syncthreads();
    }
    int base = beg + lsc[t] - v;  // global CSR start for this node slot
    lsc[t] = base;                // own-slot overwrite; consumed after the barrier below
    int nd = (b << 9) + t - m;
    if (nd >= 0 && nd < N_NODES) {
        rp[nd] = base;
        invd[nd] = 1.0f / (float)max(v, 1);
    }
    __syncthreads();
    for (int e = beg + t; e < end; e += 512) {
        unsigned p = ebuf[e];
        int loc = p & 511;
        int pos = lsc[loc] + atomicAdd(&lfill[loc], 1);
        csr[pos] = (int)(p >> 9);
    }
}

// ---------------- fp32 -> bf16 conversion (x -> xb) ----------------
__global__ void k_cvt(const float* __restrict__ x, unsigned* __restrict__ xb, int n4) {
    int i = blockIdx.x * blockDim.x + threadIdx.x;
    if (i >= n4) return;
    float4 v = *(const float4*)(x + (size_t)i * 4);
    uint2 o;
    o.x = f2bf(v.x) | (f2bf(v.y) << 16);
    o.y = f2bf(v.z) | (f2bf(v.w) << 16);
    *(uint2*)(xb + (size_t)i * 2) = o;
}

// ---------------- W -> bf16 split-precision transposed: Wt[n][k], W ~= hi + lo ----------------
__global__ void k_prep(const float* __restrict__ Wl, const float* __restrict__ Wr,
                       unsigned* __restrict__ wlh, unsigned* __restrict__ wll,
                       unsigned* __restrict__ wrh, unsigned* __restrict__ wrl) {
    int b = blockIdx.x;  // 0..2: Wl layer b; 3..5: Wr layer b-3
    int t = threadIdx.x;
    const float* src = (b < 3) ? (Wl + (size_t)b * HID * HID) : (Wr + (size_t)(b - 3) * HID * HID);
    unsigned* dh = (b < 3) ? (wlh + (size_t)b * HID * 64) : (wrh + (size_t)(b - 3) * HID * 64);
    unsigned* dl = (b < 3) ? (wll + (size_t)b * HID * 64) : (wrl + (size_t)(b - 3) * HID * 64);
    for (int i = 0; i < 32; ++i) {
        int u = t * 32 + i;           // 0..8191: n = u>>6 (out col), kk = u&63 (k pair)
        int n = u >> 6, kk = u & 63;
        float v0 = src[(size_t)(2 * kk) * HID + n];
        float v1 = src[(size_t)(2 * kk + 1) * HID + n];
        unsigned h0 = f2bf(v0), h1 = f2bf(v1);
        unsigned l0 = f2bf(v0 - bf2f(h0)), l1 = f2bf(v1 - bf2f(h1));
        dh[u] = h0 | (h1 << 16);
        dl[u] = l0 | (l1 << 16);
    }
}

// ---------------- mean aggregation: one wave per node, bf16 rows, bf16 packed output ----------------
__global__ void k_agg(const unsigned* __restrict__ hb, const int* __restrict__ rp,
                      const int* __restrict__ csr, const float* __restrict__ invd,
                      unsigned* __restrict__ aggb) {
    const int n = blockIdx.x;
    const int lane = threadIdx.x;  // 64; lane covers features 2*lane, 2*lane+1
    int beg = rp[n], end = rp[n + 1];
    float p0 = 0, p1 = 0, q0 = 0, q1 = 0, r0 = 0, r1 = 0, t0 = 0, t1 = 0;
    int e = beg;
    for (; e + 8 <= end; e += 8) {
        int s0 = csr[e], s1 = csr[e + 1], s2 = csr[e + 2], s3 = csr[e + 3];
        int s4 = csr[e + 4], s5 = csr[e + 5], s6 = csr[e + 6], s7 = csr[e + 7];
        unsigned u0 = hb[(size_t)s0 * 64 + lane];
        unsigned u1 = hb[(size_t)s1 * 64 + lane];
        unsigned u2 = hb[(size_t)s2 * 64 + lane];
        unsigned u3 = hb[(size_t)s3 * 64 + lane];
        unsigned u4 = hb[(size_t)s4 * 64 + lane];
        unsigned u5 = hb[(size_t)s5 * 64 + lane];
        unsigned u6 = hb[(size_t)s6 * 64 + lane];
        unsigned u7 = hb[(size_t)s7 * 64 + lane];
        p0 += __uint_as_float(u0 << 16); p1 += __uint_as_float(u0 & 0xFFFF0000u);
        q0 += __uint_as_float(u1 << 16); q1 += __uint_as_float(u1 & 0xFFFF0000u);
        r0 += __uint_as_float(u2 << 16); r1 += __uint_as_float(u2 & 0xFFFF0000u);
        t0 += __uint_as_float(u3 << 16); t1 += __uint_as_float(u3 & 0xFFFF0000u);
        p0 += __uint_as_float(u4 << 16); p1 += __uint_as_float(u4 & 0xFFFF0000u);
        q0 += __uint_as_float(u5 << 16); q1 += __uint_as_float(u5 & 0xFFFF0000u);
        r0 += __uint_as_float(u6 << 16); r1 += __uint_as_float(u6 & 0xFFFF0000u);
        t0 += __uint_as_float(u7 << 16); t1 += __uint_as_float(u7 & 0xFFFF0000u);
    }
    for (; e < end; ++e) {
        unsigned u = hb[(size_t)csr[e] * 64 + lane];
        p0 += __uint_as_float(u << 16);
        p1 += __uint_as_float(u & 0xFFFF0000u);
    }
    float iv = invd[n];
    unsigned o = f2bf((p0 + q0 + r0 + t0) * iv) | (f2bf((p1 + q1 + r1 + t1) * iv) << 16);
    aggb[(size_t)n * 64 + lane] = o;
}

// ---------------- MFMA fused: h_out = relu(agg@Wl + hin@Wr + b); pooled += per-graph sums ----
__global__ __launch_bounds__(256, 4) void k_gemm(
    const unsigned* __restrict__ aggb, const unsigned* __restrict__ hinb,
    const unsigned* __restrict__ wlh, const unsigned* __restrict__ wll,
    const unsigned* __restrict__ wrh, const unsigned* __restrict__ wrl,
    const float* __restrict__ bias, const int* __restrict__ batch,
    unsigned* __restrict__ houtb, float* __restrict__ pooled, int layer) {
    __shared__ float Ts[64 * 132];  // stride 132: epilogue writes <=2-way bank aliased
    __shared__ int bs[64];
    const int tx = threadIdx.x;
    const int wave = tx >> 6, lane = tx & 63;
    const int row0 = blockIdx.x * 64;
    const int lrow = lane & 15, kgrp = lane >> 4;

    if (tx < 64) {
        int grow = row0 + tx;
        bs[tx] = (grow < N_NODES) ? batch[grow] : -1;
    }

    f32x4 acc[4][2];
#pragma unroll
    for (int m = 0; m < 4; ++m)
#pragma unroll
        for (int n = 0; n < 2; ++n) acc[m][n] = (f32x4){0.f, 0.f, 0.f, 0.f};
    const short8 zf = {0, 0, 0, 0, 0, 0, 0, 0};

    for (int kc = 0; kc < 4; ++kc) {
        const int koff = kc * 16 + kgrp * 4;  // uint offset: k = kc*32 + kgrp*8 + (0..7)
        short8 af[4], hf[4];
#pragma unroll
        for (int m = 0; m < 4; ++m) {
            int r = row0 + m * 16 + lrow;
            if (r < N_NODES) {
                af[m] = *(const short8*)(aggb + (size_t)r * 64 + koff);
                hf[m] = *(const short8*)(hinb + (size_t)r * 64 + koff);
            } else {
                af[m] = zf;
                hf[m] = zf;
            }
        }
#pragma unroll
        for (int n = 0; n < 2; ++n) {
            int wn = wave * 2 + n;  // col tile 0..7
            size_t wbase = (size_t)(wn * 16 + lrow) * 64 + koff;
            short8 fl_h = *(const short8*)(wlh + wbase);
            short8 fl_l = *(const short8*)(wll + wbase);
            short8 fr_h = *(const short8*)(wrh + wbase);
            short8 fr_l = *(const short8*)(wrl + wbase);
#pragma unroll
            for (int m = 0; m < 4; ++m) {
                acc[m][n] = __builtin_amdgcn_mfma_f32_16x16x32_bf16(af[m], fl_h, acc[m][n], 0, 0, 0);
                acc[m][n] = __builtin_amdgcn_mfma_f32_16x16x32_bf16(af[m], fl_l, acc[m][n], 0, 0, 0);
                acc[m][n] = __builtin_amdgcn_mfma_f32_16x16x32_bf16(hf[m], fr_h, acc[m][n], 0, 0, 0);
                acc[m][n] = __builtin_amdgcn_mfma_f32_16x16x32_bf16(hf[m], fr_l, acc[m][n], 0, 0, 0);
            }
        }
    }

    // C/D layout: col = lane&15, row = (lane>>4)*4 + reg  [guide §3, m89-verified]
#pragma unroll
    for (int n = 0; n < 2; ++n) {
        int c = wave * 32 + n * 16 + lrow;
        float bb = bias[c];
#pragma unroll
        for (int m = 0; m < 4; ++m)
#pragma unroll
            for (int reg = 0; reg < 4; ++reg) {
                int r = m * 16 + kgrp * 4 + reg;
                Ts[r * 132 + c] = fmaxf(acc[m][n][reg] + bb, 0.f);
            }
    }
    __syncthreads();

    // bf16 h_out store, coalesced: 1024 uint4 tiles over [64][128]
#pragma unroll
    for (int it = 0; it < 4; ++it) {
        int f = it * 256 + tx;
        int r = f >> 4, slot = f & 15;
        int grow = row0 + r;
        if (grow < N_NODES) {
            const float* ts = &Ts[r * 132 + slot * 8];
            uint4 o;
            o.x = f2bf(ts[0]) | (f2bf(ts[1]) << 16);
            o.y = f2bf(ts[2]) | (f2bf(ts[3]) << 16);
            o.z = f2bf(ts[4]) | (f2bf(ts[5]) << 16);
            o.w = f2bf(ts[6]) | (f2bf(ts[7]) << 16);
            *(uint4*)(houtb + (size_t)grow * 64 + slot * 4) = o;
        }
    }

    // per-graph pooled pre-reduction (batch sorted; fp32 pre-quantization values)
    if (tx < 128) {
        int j = tx;
        float run = 0.f;
        int curb = bs[0];
        for (int r = 0; r < 64; ++r) {
            int bb = bs[r];
            if (bb != curb) {
                if (curb >= 0)
                    atomicAdd(&pooled[(size_t)curb * (HID * N_LAYER) + layer * HID + j], run);
                run = 0.f;
                curb = bb;
            }
            run += Ts[r * 132 + j];
        }
        if (curb >= 0)
            atomicAdd(&pooled[(size_t)curb * (HID * N_LAYER) + layer * HID + j], run);
    }
}

// ---------------- FC head: one block per graph ----------------
__global__ void k_fc(const float* __restrict__ pooled, const float* __restrict__ counts,
                     const float* __restrict__ fc1w, const float* __restrict__ fc1b,
                     const float* __restrict__ fc2w, const float* __restrict__ fc2b,
                     float* __restrict__ out) {
    __shared__ float pr[HID * N_LAYER];
    __shared__ float a1[FC_HID];
    const int g = blockIdx.x, t = threadIdx.x;  // 256 threads
    float invc = 1.0f / fmaxf(counts[g], 1.0f);
    for (int i = t; i < HID * N_LAYER; i += FC_HID)
        pr[i] = pooled[(size_t)g * (HID * N_LAYER) + i] * invc;
    __syncthreads();
    float acc = fc1b[t];
    for (int k = 0; k < HID * N_LAYER; ++k)
        acc = fmaf(pr[k], fc1w[(size_t)k * FC_HID + t], acc);
    a1[t] = fmaxf(acc, 0.f);
    __syncthreads();
    if (t < N_CLASS) {
        float o = fc2b[t];
        for (int k = 0; k < FC_HID; ++k)
            o = fmaf(a1[k], fc2w[(size_t)k * N_CLASS + t], o);
        out[(size_t)g * N_CLASS + t] = o;
    }
}

extern "C" void kernel_launch(void* const* d_in, const int* in_sizes, int n_in,
                              void* d_out, int out_size, void* d_ws, size_t ws_size,
                              hipStream_t stream) {
    const float* x = (const float*)d_in[0];
    const int* ei = (const int*)d_in[1];
    const int* batch = (const int*)d_in[2];
    const float* Wl = (const float*)d_in[3];
    const float* Wr = (const float*)d_in[4];
    const float* bl = (const float*)d_in[5];
    const float* fc1w = (const float*)d_in[6];
    const float* fc1b = (const float*)d_in[7];
    const float* fc2w = (const float*)d_in[8];
    const float* fc2b = (const float*)d_in[9];
    float* out = (float*)d_out;

    char* ws = (char*)d_ws;
    size_t off = 0;
    auto alloc = [&](size_t bytes) {
        void* p = ws + off;
        off += (bytes + 255) & ~size_t(255);
        return p;
    };
    int* emin = (int*)alloc(4);
    float* pooled = (float*)alloc((size_t)N_GRAPHS * HID * N_LAYER * 4);
    // ---- not zeroed (fully overwritten every call) ----
    int* hist = (int*)alloc((size_t)BIN_NB * NBKT * 4);
    int* colex = (int*)alloc((size_t)BIN_NB * NBKT * 4);
    int* btot = (int*)alloc(NBKT * 4);
    int* bboff = (int*)alloc((NBKT + 1) * 4);
    int* rp = (int*)alloc((N_NODES + 1) * 4);
    float* invd = (float*)alloc(N_NODES * 4);
    float* counts = (float*)alloc(N_GRAPHS * 4);
    unsigned* ebuf = (unsigned*)alloc((size_t)N_EDGES * 4);
    int* csr = (int*)alloc((size_t)N_EDGES * 4);
    unsigned* wlh = (unsigned*)alloc((size_t)N_LAYER * HID * 64 * 4);
    unsigned* wll = (unsigned*)alloc((size_t)N_LAYER * HID * 64 * 4);
    unsigned* wrh = (unsigned*)alloc((size_t)N_LAYER * HID * 64 * 4);
    unsigned* wrl = (unsigned*)alloc((size_t)N_LAYER * HID * 64 * 4);
    unsigned* aggb = (unsigned*)alloc((size_t)N_NODES * 64 * 4);   // bf16x2 packed
    unsigned* xb = (unsigned*)alloc((size_t)N_NODES * 64 * 4);
    unsigned* hb1 = (unsigned*)alloc((size_t)N_NODES * 64 * 4);
    unsigned* hb2 = (unsigned*)alloc((size_t)N_NODES * 64 * 4);

    // zero accumulators every call (ws is poisoned once, never re-poisoned)
    hipMemsetAsync(emin, 0x7F, 4, stream);  // 0x7F7F7F7F > max index
    hipMemsetAsync(pooled, 0, (size_t)N_GRAPHS * HID * N_LAYER * 4, stream);

    k_minh<<<BIN_NB, 512, 0, stream>>>(ei, emin, hist);
    k_base<<<NBKT, BIN_NB, 0, stream>>>(hist, colex, btot);
    k_bscan<<<1, 128, 0, stream>>>(btot, bboff, rp, batch, counts);
    k_bin<<<BIN_NB, 512, 0, stream>>>(ei, emin, bboff, colex, ebuf);
    k_scatter2<<<NBKT + 1, 512, 0, stream>>>(ebuf, bboff, emin, rp, invd, csr);
    k_cvt<<<(N_NODES * HID / 4 + 255) / 256, 256, 0, stream>>>(x, xb, N_NODES * HID / 4);
    k_prep<<<6, 256, 0, stream>>>(Wl, Wr, wlh, wll, wrh, wrl);

    const unsigned* hin = xb;
    unsigned* houts[3] = {hb1, hb2, hb1};
    for (int layer = 0; layer < N_LAYER; ++layer) {
        k_agg<<<N_NODES, 64, 0, stream>>>(hin, rp, csr, invd, aggb);
        k_gemm<<<(N_NODES + 63) / 64, 256, 0, stream>>>(
            aggb, hin,
            wlh + (size_t)layer * HID * 64, wll + (size_t)layer * HID * 64,
            wrh + (size_t)layer * HID * 64, wrl + (size_t)layer * HID * 64,
            bl + (size_t)layer * HID, batch, houts[layer], pooled, layer);
        hin = houts[layer];
    }
    k_fc<<<N_GRAPHS, 256, 0, stream>>>(pooled, counts, fc1w, fc1b, fc2w, fc2b, out);
}